// Round 8
// baseline (604.201 us; speedup 1.0000x reference)
//
#include <hip/hip_runtime.h>
#include <hip/hip_bf16.h>
#include <math.h>

// COSGATEncoder: N=50000, E=1280000, D=64, HEADS=1. f32 in/out (runtime-detected,
// bf16 fallback), edge_index int64 (runtime-detected, int32 fallback).
// R20: bucketed two-phase binning + re-fused dense work. R19 exposed k_bin at
// 109us, VALU 0.9%, WRITE 79MB (=16x amplification: scattered 4B csr2 stores
// dirty 64B lines, csr2 12.8MB >> 4MB/XCD L2). Fix: phase 1 scatters edges to
// 1024 coarse dst-range buckets (8B entries, dense line fill, ~10MB writes),
// fused into k_all with prep0+residual MLP (dense work hides in scatter stall
// shadow -- the R18 overlap effect). Phase 2 (k_bucket) re-scatters per bucket
// into csr2: target window ~12KB, L2-hot, amplification ~1. Bucket overflow ->
// in-kernel direct-scatter fallback; small workspace -> bcap=0 (direct scatter).
// Rest = R19: k_edge modes 2/3 (thin epilogues), weight-resident k_prepW,
// 1-wave blocks, slot-CSR, exact slow path deg>CAP, fp8 fhat, packed 4B csr.

constexpr int D = 64;
constexpr int CAP = 64;
constexpr int NBK = 1024;  // coarse buckets for two-phase binning
constexpr float NEG_SLOPE = 0.2f;
constexpr float EPS_COS = 1e-8f;
constexpr float EPS_SM = 1e-16f;

#if defined(__has_builtin)
#if __has_builtin(__builtin_amdgcn_cvt_pk_f32_fp8) && __has_builtin(__builtin_amdgcn_cvt_pk_fp8_f32)
#define HW_FP8 1
#endif
#endif

typedef float floatx2 __attribute__((ext_vector_type(2)));

__device__ __forceinline__ float wred_sum(float v) {
#pragma unroll
  for (int off = 32; off > 0; off >>= 1) v += __shfl_xor(v, off, 64);
  return v;
}
__device__ __forceinline__ float wred_max(float v) {
#pragma unroll
  for (int off = 32; off > 0; off >>= 1) v = fmaxf(v, __shfl_xor(v, off, 64));
  return v;
}
__device__ __forceinline__ float elu1(float x) { return x > 0.f ? x : __expf(x) - 1.f; }
__device__ __forceinline__ float sane(float v) {
  return (v == v && fabsf(v) < 1e30f) ? v : 0.f;
}
__device__ __forceinline__ float ldv(const void* p, size_t i, int f32) {
  return f32 ? ((const float*)p)[i]
             : __bfloat162float(((const __hip_bfloat16*)p)[i]);
}
__device__ __forceinline__ void stv(void* p, size_t i, int f32, float v) {
  if (f32) ((float*)p)[i] = v;
  else ((__hip_bfloat16*)p)[i] = __float2bfloat16(v);
}
__device__ __forceinline__ float b2f(unsigned short u) {
  return __uint_as_float(((unsigned int)u) << 16);
}
__device__ __forceinline__ void unp8(uint4 u, float* f) {
  f[0] = __uint_as_float(u.x << 16);
  f[1] = __uint_as_float(u.x & 0xffff0000u);
  f[2] = __uint_as_float(u.y << 16);
  f[3] = __uint_as_float(u.y & 0xffff0000u);
  f[4] = __uint_as_float(u.z << 16);
  f[5] = __uint_as_float(u.z & 0xffff0000u);
  f[6] = __uint_as_float(u.w << 16);
  f[7] = __uint_as_float(u.w & 0xffff0000u);
}

// ---- fp8 helpers: HW e4m3 when available, f16-msb (e5m2-like) fallback ----
__device__ __forceinline__ unsigned char enc_fp8(float v) {
#ifdef HW_FP8
  int pk = __builtin_amdgcn_cvt_pk_fp8_f32(v, v, 0, false);
  return (unsigned char)(pk & 0xFF);
#else
  _Float16 h = (_Float16)v;
  unsigned short ub;
  __builtin_memcpy(&ub, &h, 2);
  return (unsigned char)((ub + 0x80) >> 8);  // RNE-ish truncate to top byte
#endif
}
__device__ __forceinline__ void dec_fp8x8(uint2 u, float* f) {
#ifdef HW_FP8
  floatx2 a = __builtin_amdgcn_cvt_pk_f32_fp8(u.x, false);
  floatx2 b = __builtin_amdgcn_cvt_pk_f32_fp8(u.x, true);
  floatx2 c = __builtin_amdgcn_cvt_pk_f32_fp8(u.y, false);
  floatx2 d = __builtin_amdgcn_cvt_pk_f32_fp8(u.y, true);
  f[0] = a[0]; f[1] = a[1]; f[2] = b[0]; f[3] = b[1];
  f[4] = c[0]; f[5] = c[1]; f[6] = d[0]; f[7] = d[1];
#else
#pragma unroll
  for (int i = 0; i < 8; ++i) {
    unsigned int byte = (i < 4 ? (u.x >> (8 * i)) : (u.y >> (8 * (i - 4)))) & 0xFF;
    unsigned short hb = (unsigned short)(byte << 8);
    _Float16 h;
    __builtin_memcpy(&h, &hb, 2);
    f[i] = (float)h;
  }
#endif
}

// packed csr entry: bits 0..17 = src, bits 18..31 = gate quantized to 14 bits
__device__ __forceinline__ unsigned int pack_sg(int src, float g) {
  int gq = (int)(g * 16383.f + 0.5f);
  return ((unsigned int)src & 0x3FFFFu) | ((unsigned int)gq << 18);
}
__device__ __forceinline__ int upk_src(unsigned int e, int N) {
  return min((int)(e & 0x3FFFFu), N - 1);
}
__device__ __forceinline__ float upk_gate(unsigned int e) {
  return (float)(e >> 18) * (1.f / 16383.f);
}
__device__ __forceinline__ float gate_of(float w) {
  return fminf(fmaxf(1.f - 0.25f * fminf(w, 4.f), 0.f), 1.f);
}

// full fp8-row cosine dot (slow path only)
__device__ float slow_cos(const unsigned char* __restrict__ fhat, int a, int b) {
  const uint2* fa = (const uint2*)(fhat + (size_t)a * D);
  const uint2* fb = (const uint2*)(fhat + (size_t)b * D);
  float dsum = 0.f;
  for (int q = 0; q < 8; ++q) {
    float va[8], vb[8];
    dec_fp8x8(fa[q], va);
    dec_fp8x8(fb[q], vb);
#pragma unroll
    for (int i = 0; i < 8; ++i) dsum += va[i] * vb[i];
  }
  return dsum;
}

// shared prep body: LDS-broadcast GEMM (ends with __syncthreads; ls reusable)
__device__ __forceinline__ void prep_node(float f, int f32, int wid, int lane,
                                          const void* __restrict__ W,
                                          const void* __restrict__ att,
                                          unsigned char* __restrict__ fhat,
                                          __hip_bfloat16* __restrict__ Hmat,
                                          float* __restrict__ a_l,
                                          float* __restrict__ a_r,
                                          float* __restrict__ ls) {
  float n2 = wred_sum(f * f);
  float nrm = fmaxf(sqrtf(n2), EPS_COS);
  fhat[(size_t)wid * D + lane] = enc_fp8(f / nrm);
  ls[lane] = f;
  __syncthreads();
  float h0 = 0.f, h1 = 0.f, h2 = 0.f, h3 = 0.f;
  if (f32) {
    const float* Wf = (const float*)W;
#pragma unroll 4
    for (int k = 0; k < D; k += 4) {
      h0 += ls[k] * Wf[k * D + lane];
      h1 += ls[k + 1] * Wf[(k + 1) * D + lane];
      h2 += ls[k + 2] * Wf[(k + 2) * D + lane];
      h3 += ls[k + 3] * Wf[(k + 3) * D + lane];
    }
  } else {
    const __hip_bfloat16* Wb = (const __hip_bfloat16*)W;
#pragma unroll 4
    for (int k = 0; k < D; k += 4) {
      h0 += ls[k] * __bfloat162float(Wb[k * D + lane]);
      h1 += ls[k + 1] * __bfloat162float(Wb[(k + 1) * D + lane]);
      h2 += ls[k + 2] * __bfloat162float(Wb[(k + 2) * D + lane]);
      h3 += ls[k + 3] * __bfloat162float(Wb[(k + 3) * D + lane]);
    }
  }
  float Hc = (h0 + h1) + (h2 + h3);
  Hmat[(size_t)wid * D + lane] = __float2bfloat16(Hc);
  float al = wred_sum(Hc * ldv(att, lane, f32));
  float ar = wred_sum(Hc * ldv(att, D + lane, f32));
  if (lane == 0) {
    a_l[wid] = al;
    a_r[wid] = ar;
  }
  __syncthreads();
}

// ---------------- R20: fused front kernel ----------------
// grid=N, 64 threads. Block b: dtype detect + bucket-scatter its edge chunk
// (phase 1) + prep node b (W0) + residual MLP node b (rW1,rW2) -> xres.
// bcap==0 => direct scatter into csr2 (fallback).
__global__ void __launch_bounds__(64) k_all(const unsigned short* __restrict__ xu,
                                            const int* __restrict__ ei,
                                            const void* __restrict__ w,
                                            int* __restrict__ flags,
                                            int* __restrict__ cnt,
                                            int* __restrict__ bcnt,
                                            uint2* __restrict__ bkt, int bcap,
                                            const void* __restrict__ x,
                                            const void* __restrict__ W,
                                            const void* __restrict__ att,
                                            const void* __restrict__ rW1,
                                            const void* __restrict__ rb1,
                                            const void* __restrict__ rW2,
                                            const void* __restrict__ rb2,
                                            unsigned char* __restrict__ fhat,
                                            __hip_bfloat16* __restrict__ Hmat,
                                            float* __restrict__ a_l,
                                            float* __restrict__ a_r,
                                            float* __restrict__ xres,
                                            unsigned int* __restrict__ csr2,
                                            int N, int E) {
  __shared__ float ls[D];
  const int lane = threadIdx.x;
  const int b = blockIdx.x;
  // dtype detect: per-wave, register-only (x[0..63] / ei[0..127] are L2-hot)
  float dv = b2f(xu[lane]);
  float da = fabsf(dv);
  unsigned long long m = __ballot(da > 1e-4f && da < 100.f);
  unsigned long long m2 = __ballot(ei[2 * lane + 1] != 0);
  const int f32 = (__popcll(m) >= 60) ? 0 : 1;
  const int wide = (m2 == 0ull) ? 1 : 0;
  if (b == 0 && lane == 0) {
    flags[0] = f32;
    flags[1] = wide;
  }
  // ---- phase-1 binning: edge chunk -> coarse buckets (dense 8B stores) ----
  const long long e0 = ((long long)b * E) / N;
  const long long e1 = ((long long)(b + 1) * E) / N;
  for (long long e = e0 + lane; e < e1; e += 64) {
    int ss, dd;
    if (wide) {
      ss = ei[2 * e];
      dd = ei[2 * (size_t)E + 2 * e];
    } else {
      ss = ei[e];
      dd = ei[(size_t)E + e];
    }
    float we = ldv(w, (size_t)e, f32);
    const int dc = min(max(dd, 0), N - 1);
    const unsigned int sg = pack_sg(min(max(ss, 0), N - 1), gate_of(we));
    bool direct = true;
    if (bcap > 0) {
      const int bu = (int)(((long long)dc * NBK) / N);
      const int pos = atomicAdd(&bcnt[bu], 1);
      if (pos < bcap) {
        bkt[(size_t)bu * bcap + pos] = make_uint2(sg, (unsigned)dc);
        direct = false;
      }
    }
    if (direct) {  // fallback: direct scatter (bucket overflow or bcap==0)
      const int slot = atomicAdd(&cnt[dc], 1);
      if (slot < CAP) csr2[(size_t)dc * CAP + slot] = sg;
    }
  }
  if (b >= N) return;
  // ---- node prep (layer 0) ----
  float f = ldv(x, (size_t)b * D + lane, f32);
  prep_node(f, f32, b, lane, W, att, fhat, Hmat, a_l, a_r, ls);
  // ---- residual MLP: xres = relu(x@rW1+rb1)@rW2+rb2 (reuses f = x[b]) ----
  ls[lane] = f;
  __syncthreads();
  float h0 = ldv(rb1, lane, f32), h1 = 0.f, h2 = 0.f, h3 = 0.f;
  if (f32) {
    const float* w1 = (const float*)rW1;
#pragma unroll 4
    for (int k = 0; k < D; k += 4) {
      h0 += ls[k] * w1[k * D + lane];
      h1 += ls[k + 1] * w1[(k + 1) * D + lane];
      h2 += ls[k + 2] * w1[(k + 2) * D + lane];
      h3 += ls[k + 3] * w1[(k + 3) * D + lane];
    }
  } else {
    const __hip_bfloat16* w1 = (const __hip_bfloat16*)rW1;
#pragma unroll 4
    for (int k = 0; k < D; k += 4) {
      h0 += ls[k] * __bfloat162float(w1[k * D + lane]);
      h1 += ls[k + 1] * __bfloat162float(w1[(k + 1) * D + lane]);
      h2 += ls[k + 2] * __bfloat162float(w1[(k + 2) * D + lane]);
      h3 += ls[k + 3] * __bfloat162float(w1[(k + 3) * D + lane]);
    }
  }
  float tr = fmaxf((h0 + h1) + (h2 + h3), 0.f);
  __syncthreads();
  ls[lane] = tr;
  __syncthreads();
  float g0 = ldv(rb2, lane, f32), g1 = 0.f, g2 = 0.f, g3 = 0.f;
  if (f32) {
    const float* w2 = (const float*)rW2;
#pragma unroll 4
    for (int k = 0; k < D; k += 4) {
      g0 += ls[k] * w2[k * D + lane];
      g1 += ls[k + 1] * w2[(k + 1) * D + lane];
      g2 += ls[k + 2] * w2[(k + 2) * D + lane];
      g3 += ls[k + 3] * w2[(k + 3) * D + lane];
    }
  } else {
    const __hip_bfloat16* w2 = (const __hip_bfloat16*)rW2;
#pragma unroll 4
    for (int k = 0; k < D; k += 4) {
      g0 += ls[k] * __bfloat162float(w2[k * D + lane]);
      g1 += ls[k + 1] * __bfloat162float(w2[(k + 1) * D + lane]);
      g2 += ls[k + 2] * __bfloat162float(w2[(k + 2) * D + lane]);
      g3 += ls[k + 3] * __bfloat162float(w2[(k + 3) * D + lane]);
    }
  }
  xres[(size_t)b * D + lane] = (g0 + g1) + (g2 + g3);
}

// ---------------- R20: phase-2 bucket -> csr2 (L2-hot window scatter) ----------------
__global__ void __launch_bounds__(256) k_bucket(const int* __restrict__ bcnt,
                                                const uint2* __restrict__ bkt, int bcap,
                                                int* __restrict__ cnt,
                                                unsigned int* __restrict__ csr2, int N) {
  const int bu = blockIdx.x;
  const int n = min(bcnt[bu], bcap);
  const uint2* base = bkt + (size_t)bu * bcap;
  for (int i = threadIdx.x; i < n; i += 256) {
    uint2 en = base[i];
    const int dc = min((int)en.y, N - 1);
    const int slot = atomicAdd(&cnt[dc], 1);
    if (slot < CAP) csr2[(size_t)dc * CAP + slot] = en.x;
  }
}

// ---------------- legacy binning kernel (fallback tiers) ----------------
__global__ void __launch_bounds__(256) k_bin(const unsigned short* __restrict__ xu,
                                             const int* __restrict__ ei,
                                             const void* __restrict__ w,
                                             int* __restrict__ flags,
                                             int* __restrict__ cnt,
                                             unsigned int* __restrict__ csr2,
                                             int N, int E) {
  __shared__ int sf[2];
  const int tid = threadIdx.x;
  if (tid < 64) {
    float v = b2f(xu[tid]);
    float a = fabsf(v);
    unsigned long long m = __ballot(a > 1e-4f && a < 100.f);
    unsigned long long m2 = __ballot(ei[2 * tid + 1] != 0);
    if (tid == 0) {
      sf[0] = (__popcll(m) >= 60) ? 0 : 1;  // 1 => f32
      sf[1] = (m2 == 0ull) ? 1 : 0;         // 1 => int64
      if (blockIdx.x == 0) {
        flags[0] = sf[0];
        flags[1] = sf[1];
      }
    }
  }
  __syncthreads();
  const int f32 = sf[0], wide = sf[1];
  const int e0 = (blockIdx.x * 256 + tid) * 2;
  if (e0 >= E) return;
  const bool has1 = (e0 + 1 < E);
  int s0, s1, d0, d1;
  if (wide) {
    int4 vs = *(const int4*)(ei + 2 * (size_t)e0);
    int4 vd = *(const int4*)(ei + 2 * (size_t)E + 2 * (size_t)e0);
    s0 = vs.x; s1 = vs.z; d0 = vd.x; d1 = vd.z;
  } else {
    int2 vs = *(const int2*)(ei + e0);
    int2 vd = *(const int2*)(ei + (size_t)E + e0);
    s0 = vs.x; s1 = vs.y; d0 = vd.x; d1 = vd.y;
  }
  float w0, w1 = 0.f;
  if (f32) {
    float2 wv = *(const float2*)((const float*)w + e0);
    w0 = wv.x; w1 = wv.y;
  } else {
    const __hip_bfloat16* wb = (const __hip_bfloat16*)w;
    w0 = __bfloat162float(wb[e0]);
    if (has1) w1 = __bfloat162float(wb[e0 + 1]);
  }
  int d0c = min(max(d0, 0), N - 1);
  int slot0 = atomicAdd(&cnt[d0c], 1);
  if (slot0 < CAP)
    csr2[(size_t)d0c * CAP + slot0] = pack_sg(min(max(s0, 0), N - 1), gate_of(w0));
  if (has1) {
    int d1c = min(max(d1, 0), N - 1);
    int slot1 = atomicAdd(&cnt[d1c], 1);
    if (slot1 < CAP)
      csr2[(size_t)d1c * CAP + slot1] = pack_sg(min(max(s1, 0), N - 1), gate_of(w1));
  }
}

// ---------------- weight-resident node prep (grid-stride) ----------------
__global__ void __launch_bounds__(64, 4) k_prepW(const void* __restrict__ xin,
                                                 const void* __restrict__ W,
                                                 const void* __restrict__ att,
                                                 const int* __restrict__ flags,
                                                 unsigned char* __restrict__ fhat,
                                                 __hip_bfloat16* __restrict__ Hmat,
                                                 float* __restrict__ a_l,
                                                 float* __restrict__ a_r, int N) {
  __shared__ float ls[D];
  const int lane = threadIdx.x;
  const int f32 = flags[0];
  float wreg[D];
  if (f32) {
    const float* Wf = (const float*)W;
#pragma unroll
    for (int k = 0; k < D; ++k) wreg[k] = Wf[k * D + lane];
  } else {
    const __hip_bfloat16* Wb = (const __hip_bfloat16*)W;
#pragma unroll
    for (int k = 0; k < D; ++k) wreg[k] = __bfloat162float(Wb[k * D + lane]);
  }
  const float attl = ldv(att, lane, f32);
  const float attr = ldv(att, D + lane, f32);
  float f = (blockIdx.x < (unsigned)N) ? ldv(xin, (size_t)blockIdx.x * D + lane, f32) : 0.f;
  for (int wid = blockIdx.x; wid < N; wid += gridDim.x) {
    const int nwid = wid + gridDim.x;
    float fnx = (nwid < N) ? ldv(xin, (size_t)nwid * D + lane, f32) : 0.f;  // prefetch
    float n2 = wred_sum(f * f);
    float nrm = fmaxf(sqrtf(n2), EPS_COS);
    fhat[(size_t)wid * D + lane] = enc_fp8(f / nrm);
    ls[lane] = f;
    __syncthreads();
    float h0 = 0.f, h1 = 0.f, h2 = 0.f, h3 = 0.f;
#pragma unroll
    for (int k = 0; k < D; k += 4) {
      h0 += ls[k] * wreg[k];
      h1 += ls[k + 1] * wreg[k + 1];
      h2 += ls[k + 2] * wreg[k + 2];
      h3 += ls[k + 3] * wreg[k + 3];
    }
    float Hc = (h0 + h1) + (h2 + h3);
    Hmat[(size_t)wid * D + lane] = __float2bfloat16(Hc);
    float al = wred_sum(Hc * attl);
    float ar = wred_sum(Hc * attr);
    if (lane == 0) {
      a_l[wid] = al;
      a_r[wid] = ar;
    }
    __syncthreads();
    f = fnx;
  }
}

// standalone prep (legacy non-fused tier) — 64-thread, grid=N
__global__ void __launch_bounds__(64) k_prep(const void* __restrict__ xin,
                                             const void* __restrict__ W,
                                             const void* __restrict__ att,
                                             const int* __restrict__ flags,
                                             unsigned char* __restrict__ fhat,
                                             __hip_bfloat16* __restrict__ Hmat,
                                             float* __restrict__ a_l,
                                             float* __restrict__ a_r, int N) {
  __shared__ float ls[D];
  const int lane = threadIdx.x;
  const int wid = blockIdx.x;
  if (wid >= N) return;
  const int f32 = flags[0];
  float f = ldv(xin, (size_t)wid * D + lane, f32);
  prep_node(f, f32, wid, lane, W, att, fhat, Hmat, a_l, a_r, ls);
}

// ---------------- edge kernel: ONE wave per dst node (64-thread blocks) ----------------
// modes: 0=prep epilogue (legacy), 1=in-kernel MLP (legacy), 2=store double-elu,
//        3=v + xres -> out (main path)
__global__ void __launch_bounds__(64, 8) k_edge(const int* __restrict__ cnt,
                                                const unsigned int* __restrict__ csr2,
                                                const int* __restrict__ ei,
                                                const void* __restrict__ w,
                                                const unsigned char* __restrict__ fhat,
                                                const __hip_bfloat16* __restrict__ Hmat,
                                                const float* __restrict__ a_l,
                                                const float* __restrict__ a_r,
                                                const void* __restrict__ beta,
                                                const void* __restrict__ bias,
                                                const void* __restrict__ x,
                                                const void* __restrict__ rW1,
                                                const void* __restrict__ rb1,
                                                const void* __restrict__ rW2,
                                                const void* __restrict__ rb2,
                                                const void* __restrict__ Wn,
                                                const void* __restrict__ attn,
                                                unsigned char* __restrict__ fh2,
                                                __hip_bfloat16* __restrict__ Hm2,
                                                float* __restrict__ al2,
                                                float* __restrict__ ar2,
                                                const float* __restrict__ xres,
                                                const int* __restrict__ flags,
                                                void* __restrict__ out,
                                                int N, int E, int mode) {
  const int lane = threadIdx.x;
  const int wid = blockIdx.x;
  __shared__ float2 lc[CAP];  // (l, c) per edge
  __shared__ float2 sg[CAP];  // (src bits, p) — written in phase 2
  __shared__ float lds_t[D];  // acc transpose; reused as GEMM staging in epilogue
  if (wid >= N) return;
  const int f32 = flags[0];
  const int g = lane >> 3;   // edge slot in 8-edge group
  const int sub = lane & 7;  // feature block: [8*sub, 8*sub+8)
  const int degRaw = cnt[wid];
  const float aln = a_l[wid];
  const float bb = 1.f / (1.f + __expf(-ldv(beta, 0, f32)));
  const float ob = 1.f - bb;
  const char* HmatB = (const char*)Hmat;

  float v;  // pre-elu output feature for this lane
  if (degRaw <= CAP) {
    // ================= fast path (always taken on bench data) =================
    const int deg = degRaw;
    const int s = wid * CAP;
    float fn[8];
    dec_fp8x8(*(const uint2*)(fhat + (((unsigned)wid << 6) | ((unsigned)sub << 3))), fn);

    // ---- phase 1 (iters 0-3, static): fp8 gathers + Hmat prefetch to regs ----
    float m1 = -1e30f, m2 = -1e30f;
    uint4 hm[4];
#pragma unroll
    for (int kk = 0; kk < 4; ++kk) {
      const int base = kk * 8;
      if (base < deg) {
        const int j = base + g;
        const bool val = j < deg;
        const unsigned int en = val ? csr2[s + j] : (unsigned int)wid;
        const unsigned src = (unsigned)upk_src(en, N);
        float hv[8];
        dec_fp8x8(*(const uint2*)(fhat + ((src << 6) | ((unsigned)sub << 3))), hv);
        hm[kk] = *(const uint4*)(HmatB + ((src << 7) | ((unsigned)sub << 4)));
        float d = 0.f;
#pragma unroll
        for (int i = 0; i < 8; ++i) d += fn[i] * hv[i];
        d += __shfl_xor(d, 1, 64);
        d += __shfl_xor(d, 2, 64);
        d += __shfl_xor(d, 4, 64);
        float l = aln + a_r[src];
        l = (l >= 0.f) ? l : NEG_SLOPE * l;
        if (val) {
          m1 = fmaxf(m1, l);
          m2 = fmaxf(m2, d);
          if (sub == 0) lc[j] = make_float2(l, d);
        }
      }
    }
    // tail iterations (deg > 32): no prefetch
    for (int base = 32; base < deg; base += 8) {
      const int j = base + g;
      const bool val = j < deg;
      const unsigned int en = val ? csr2[s + j] : (unsigned int)wid;
      const unsigned src = (unsigned)upk_src(en, N);
      float hv[8];
      dec_fp8x8(*(const uint2*)(fhat + ((src << 6) | ((unsigned)sub << 3))), hv);
      float d = 0.f;
#pragma unroll
      for (int i = 0; i < 8; ++i) d += fn[i] * hv[i];
      d += __shfl_xor(d, 1, 64);
      d += __shfl_xor(d, 2, 64);
      d += __shfl_xor(d, 4, 64);
      float l = aln + a_r[src];
      l = (l >= 0.f) ? l : NEG_SLOPE * l;
      if (val) {
        m1 = fmaxf(m1, l);
        m2 = fmaxf(m2, d);
        if (sub == 0) lc[j] = make_float2(l, d);
      }
    }
    m1 = fmaxf(m1, __shfl_xor(m1, 8, 64));
    m1 = fmaxf(m1, __shfl_xor(m1, 16, 64));
    m1 = fmaxf(m1, __shfl_xor(m1, 32, 64));
    m2 = fmaxf(m2, __shfl_xor(m2, 8, 64));
    m2 = fmaxf(m2, __shfl_xor(m2, 16, 64));
    m2 = fmaxf(m2, __shfl_xor(m2, 32, 64));

    // ---- phase 2: dual softmax sums + fused p (deg <= 64 always) ----
    float el0 = 0.f, ec0 = 0.f, gg0 = 0.f;
    int q0 = 0;
    float ps1 = 0.f, ps2 = 0.f;
    if (lane < deg) {
      const unsigned int en = csr2[s + lane];  // coalesced, L2-hot
      q0 = upk_src(en, N);
      gg0 = upk_gate(en);
      float2 t = lc[lane];
      el0 = __expf(t.x - m1);
      ec0 = __expf(t.y - m2);
      ps1 = el0;
      ps2 = ec0;
    }
    const float rs1 = 1.f / (wred_sum(ps1) + EPS_SM);
    const float rs2 = 1.f / (wred_sum(ps2) + EPS_SM);

    float sp = 0.f;
    if (lane < deg) {
      float tt = (ob * el0 * rs1 + bb * ec0 * rs2) * gg0;
      float p0 = __expf(tt - 1.f);
      sp = p0;
      sg[lane] = make_float2(__int_as_float(q0), p0);  // (src, p)
    }
    const float rinv = 1.f / (wred_sum(sp) + EPS_SM);

    // ---- phase 3: register-resident Hmat for iters 0-3; gathers for tail ----
    float acc[8] = {0.f, 0.f, 0.f, 0.f, 0.f, 0.f, 0.f, 0.f};
#pragma unroll
    for (int kk = 0; kk < 4; ++kk) {
      const int base = kk * 8;
      if (base < deg) {
        const int j = base + g;
        const float pv = (j < deg) ? sg[j].y : 0.f;
        float hv[8];
        unp8(hm[kk], hv);
#pragma unroll
        for (int i = 0; i < 8; ++i) acc[i] += pv * hv[i];
      }
    }
    for (int base = 32; base < deg; base += 8) {
      const int j = base + g;
      float2 en = (j < deg) ? sg[j] : make_float2(__int_as_float(wid), 0.f);
      const float pv = en.y;
      const unsigned srcv = (unsigned)__float_as_int(en.x);
      float hv[8];
      unp8(*(const uint4*)(HmatB + ((srcv << 7) | ((unsigned)sub << 4))), hv);
#pragma unroll
      for (int i = 0; i < 8; ++i) acc[i] += pv * hv[i];
    }
#pragma unroll
    for (int i = 0; i < 8; ++i) {
      acc[i] += __shfl_xor(acc[i], 8, 64);
      acc[i] += __shfl_xor(acc[i], 16, 64);
      acc[i] += __shfl_xor(acc[i], 32, 64);
    }
    if (g == 0) {
#pragma unroll
      for (int i = 0; i < 8; ++i) lds_t[8 * sub + i] = acc[i];
    }
    v = lds_t[lane] * rinv + ldv(bias, lane, f32);
  } else {
    // ============ slow path: exact 3-pass over raw edge list ============
    const int wide = flags[1];
    lds_t[lane] = 0.f;
    float m1 = -1e30f, m2 = -1e30f;
    for (int e64 = lane; e64 < E; e64 += 64) {
      int dd = wide ? ei[2 * (size_t)E + 2 * (size_t)e64] : ei[(size_t)E + e64];
      if (dd != wid) continue;
      int ss = wide ? ei[2 * (size_t)e64] : ei[e64];
      ss = min(max(ss, 0), N - 1);
      float l = aln + a_r[ss];
      l = (l >= 0.f) ? l : NEG_SLOPE * l;
      float c = slow_cos(fhat, wid, ss);
      m1 = fmaxf(m1, l);
      m2 = fmaxf(m2, c);
    }
    m1 = wred_max(m1);
    m2 = wred_max(m2);
    float ps1 = 0.f, ps2 = 0.f;
    for (int e64 = lane; e64 < E; e64 += 64) {
      int dd = wide ? ei[2 * (size_t)E + 2 * (size_t)e64] : ei[(size_t)E + e64];
      if (dd != wid) continue;
      int ss = wide ? ei[2 * (size_t)e64] : ei[e64];
      ss = min(max(ss, 0), N - 1);
      float l = aln + a_r[ss];
      l = (l >= 0.f) ? l : NEG_SLOPE * l;
      float c = slow_cos(fhat, wid, ss);
      ps1 += __expf(l - m1);
      ps2 += __expf(c - m2);
    }
    const float rs1 = 1.f / (wred_sum(ps1) + EPS_SM);
    const float rs2 = 1.f / (wred_sum(ps2) + EPS_SM);
    float sp = 0.f;
    for (int e64 = lane; e64 < E; e64 += 64) {
      int dd = wide ? ei[2 * (size_t)E + 2 * (size_t)e64] : ei[(size_t)E + e64];
      if (dd != wid) continue;
      int ss = wide ? ei[2 * (size_t)e64] : ei[e64];
      ss = min(max(ss, 0), N - 1);
      float l = aln + a_r[ss];
      l = (l >= 0.f) ? l : NEG_SLOPE * l;
      float c = slow_cos(fhat, wid, ss);
      float gx = gate_of(ldv(w, e64, f32));
      float px = __expf((ob * __expf(l - m1) * rs1 + bb * __expf(c - m2) * rs2) * gx - 1.f);
      sp += px;
      for (int q = 0; q < D; ++q)
        atomicAdd(&lds_t[q], px * __bfloat162float(Hmat[(size_t)ss * D + q]));
    }
    const float rinv = 1.f / (wred_sum(sp) + EPS_SM);
    v = lds_t[lane] * rinv + ldv(bias, lane, f32);
  }

  v = elu1(v);  // elu inside _cosgat
  if (mode == 3) {
    float a2 = xres[(size_t)wid * D + lane];
    stv(out, (size_t)wid * D + lane, f32, sane(v + a2));
  } else if (mode == 1) {
    // legacy: fused residual MLP — LDS-broadcast GEMMs
    float xv = ldv(x, (size_t)wid * D + lane, f32);
    float b0_ = ldv(rb1, lane, f32);
    __syncthreads();
    lds_t[lane] = xv;
    __syncthreads();
    float a2;
    float h0 = 0.f, h1 = 0.f, h2 = 0.f, h3 = 0.f;
    if (f32) {
      const float* w1 = (const float*)rW1;
      const float* w2 = (const float*)rW2;
#pragma unroll 4
      for (int k = 0; k < D; k += 4) {
        h0 += lds_t[k] * w1[k * D + lane];
        h1 += lds_t[k + 1] * w1[(k + 1) * D + lane];
        h2 += lds_t[k + 2] * w1[(k + 2) * D + lane];
        h3 += lds_t[k + 3] * w1[(k + 3) * D + lane];
      }
      float tr = fmaxf(b0_ + (h0 + h1) + (h2 + h3), 0.f);
      __syncthreads();
      lds_t[lane] = tr;
      __syncthreads();
      float g0 = 0.f, g1 = 0.f, g2 = 0.f, g3 = 0.f;
#pragma unroll 4
      for (int k = 0; k < D; k += 4) {
        g0 += lds_t[k] * w2[k * D + lane];
        g1 += lds_t[k + 1] * w2[(k + 1) * D + lane];
        g2 += lds_t[k + 2] * w2[(k + 2) * D + lane];
        g3 += lds_t[k + 3] * w2[(k + 3) * D + lane];
      }
      a2 = ((const float*)rb2)[lane] + (g0 + g1) + (g2 + g3);
    } else {
      const __hip_bfloat16* w1 = (const __hip_bfloat16*)rW1;
      const __hip_bfloat16* w2 = (const __hip_bfloat16*)rW2;
#pragma unroll 4
      for (int k = 0; k < D; k += 4) {
        h0 += lds_t[k] * __bfloat162float(w1[k * D + lane]);
        h1 += lds_t[k + 1] * __bfloat162float(w1[(k + 1) * D + lane]);
        h2 += lds_t[k + 2] * __bfloat162float(w1[(k + 2) * D + lane]);
        h3 += lds_t[k + 3] * __bfloat162float(w1[(k + 3) * D + lane]);
      }
      float tr = fmaxf(b0_ + (h0 + h1) + (h2 + h3), 0.f);
      __syncthreads();
      lds_t[lane] = tr;
      __syncthreads();
      float g0 = 0.f, g1 = 0.f, g2 = 0.f, g3 = 0.f;
#pragma unroll 4
      for (int k = 0; k < D; k += 4) {
        g0 += lds_t[k] * __bfloat162float(w2[k * D + lane]);
        g1 += lds_t[k + 1] * __bfloat162float(w2[(k + 1) * D + lane]);
        g2 += lds_t[k + 2] * __bfloat162float(w2[(k + 2) * D + lane]);
        g3 += lds_t[k + 3] * __bfloat162float(w2[(k + 3) * D + lane]);
      }
      a2 = __bfloat162float(((const __hip_bfloat16*)rb2)[lane]) + (g0 + g1) + (g2 + g3);
    }
    stv(out, (size_t)wid * D + lane, f32, sane(v + a2));
  } else {
    v = elu1(v);  // inter-layer elu
    if (mode == 0) {
      __syncthreads();
      prep_node(sane(v), f32, wid, lane, Wn, attn, fh2, Hm2, al2, ar2, lds_t);
    } else {  // mode 2: store double-elu (to hbuf or out)
      stv(out, (size_t)wid * D + lane, f32, sane(v));
    }
  }
}

extern "C" void kernel_launch(void* const* d_in, const int* in_sizes, int n_in,
                              void* d_out, int out_size, void* d_ws, size_t ws_size,
                              hipStream_t stream) {
  const void* x = d_in[0];
  const int* ei = (const int*)d_in[1];
  const void* w = d_in[2];
  const void* W0 = d_in[3];
  const void* att0 = d_in[4];
  const void* beta0 = d_in[5];
  const void* b0 = d_in[6];
  const void* W1 = d_in[7];
  const void* att1 = d_in[8];
  const void* beta1 = d_in[9];
  const void* b1 = d_in[10];
  const void* rW1 = d_in[11];
  const void* rb1 = d_in[12];
  const void* rW2 = d_in[13];
  const void* rb2 = d_in[14];

  const int N = in_sizes[0] / D;
  const int E = in_sizes[2];

  char* base = (char*)d_ws;
  size_t off = 0;
  auto alloc = [&](size_t bytes) -> void* {
    void* p = base + off;
    off += (bytes + 255) & ~(size_t)255;
    return p;
  };
  // common tier
  int* flags = (int*)alloc(256);
  int* cnt = (int*)alloc((size_t)N * 4);
  unsigned int* csr2 = (unsigned int*)alloc((size_t)N * CAP * 4);
  unsigned char* fhat = (unsigned char*)alloc((size_t)N * D);
  __hip_bfloat16* Hmat = (__hip_bfloat16*)alloc((size_t)N * D * 2);
  float* a_l = (float*)alloc((size_t)N * 4);
  float* a_r = (float*)alloc((size_t)N * 4);
  const size_t common_off = off;
  // tier A: hbuf + xres (+ optional buckets)
  float* hbuf = (float*)alloc((size_t)N * D * 4);
  float* xres = (float*)alloc((size_t)N * D * 4);
  const bool tierA = (off <= ws_size);
  const int bcap = 2 * (E / NBK) + 64;
  int* bcnt = (int*)alloc((size_t)NBK * 4);
  uint2* bkt = (uint2*)alloc((size_t)NBK * (size_t)bcap * 8);
  const bool tierBk = (off <= ws_size);
  // tier B (legacy fused): second-layer prep buffers (alias tier-A region)
  off = common_off;
  unsigned char* fhat2 = (unsigned char*)alloc((size_t)N * D);
  __hip_bfloat16* Hmat2 = (__hip_bfloat16*)alloc((size_t)N * D * 2);
  float* a_l2 = (float*)alloc((size_t)N * 4);
  float* a_r2 = (float*)alloc((size_t)N * 4);
  const bool tierB = (off <= ws_size);

  const int eb2 = (E / 2 + 255) / 256;

  hipMemsetAsync(cnt, 0, (size_t)N * 4, stream);

  if (tierA) {
    const int usedBcap = tierBk ? bcap : 0;
    if (tierBk) hipMemsetAsync(bcnt, 0, (size_t)NBK * 4, stream);
    k_all<<<N, 64, 0, stream>>>((const unsigned short*)x, ei, w, flags, cnt,
                                bcnt, bkt, usedBcap, x, W0, att0,
                                rW1, rb1, rW2, rb2,
                                fhat, Hmat, a_l, a_r, xres, csr2, N, E);
    if (tierBk) k_bucket<<<NBK, 256, 0, stream>>>(bcnt, bkt, bcap, cnt, csr2, N);
    k_edge<<<N, 64, 0, stream>>>(cnt, csr2, ei, w, fhat, Hmat, a_l, a_r,
                                 beta0, b0, x, rW1, rb1, rW2, rb2,
                                 nullptr, nullptr, nullptr, nullptr, nullptr, nullptr,
                                 nullptr, flags, hbuf, N, E, 2);
    k_prepW<<<4096, 64, 0, stream>>>(hbuf, W1, att1, flags, fhat, Hmat, a_l, a_r, N);
    k_edge<<<N, 64, 0, stream>>>(cnt, csr2, ei, w, fhat, Hmat, a_l, a_r,
                                 beta1, b1, x, rW1, rb1, rW2, rb2,
                                 nullptr, nullptr, nullptr, nullptr, nullptr, nullptr,
                                 xres, flags, d_out, N, E, 3);
  } else if (tierB) {
    k_bin<<<eb2, 256, 0, stream>>>((const unsigned short*)x, ei, w, flags, cnt,
                                   csr2, N, E);
    k_prep<<<N, 64, 0, stream>>>(x, W0, att0, flags, fhat, Hmat, a_l, a_r, N);
    k_edge<<<N, 64, 0, stream>>>(cnt, csr2, ei, w, fhat, Hmat, a_l, a_r,
                                 beta0, b0, x, rW1, rb1, rW2, rb2,
                                 W1, att1, fhat2, Hmat2, a_l2, a_r2,
                                 nullptr, flags, d_out, N, E, 0);
    k_edge<<<N, 64, 0, stream>>>(cnt, csr2, ei, w, fhat2, Hmat2, a_l2, a_r2,
                                 beta1, b1, x, rW1, rb1, rW2, rb2,
                                 nullptr, nullptr, nullptr, nullptr, nullptr, nullptr,
                                 nullptr, flags, d_out, N, E, 1);
  } else {
    k_bin<<<eb2, 256, 0, stream>>>((const unsigned short*)x, ei, w, flags, cnt,
                                   csr2, N, E);
    k_prep<<<N, 64, 0, stream>>>(x, W0, att0, flags, fhat, Hmat, a_l, a_r, N);
    k_edge<<<N, 64, 0, stream>>>(cnt, csr2, ei, w, fhat, Hmat, a_l, a_r,
                                 beta0, b0, x, rW1, rb1, rW2, rb2,
                                 nullptr, nullptr, nullptr, nullptr, nullptr, nullptr,
                                 nullptr, flags, d_out, N, E, 2);
    k_prep<<<N, 64, 0, stream>>>(d_out, W1, att1, flags, fhat, Hmat, a_l, a_r, N);
    k_edge<<<N, 64, 0, stream>>>(cnt, csr2, ei, w, fhat, Hmat, a_l, a_r,
                                 beta1, b1, x, rW1, rb1, rW2, rb2,
                                 nullptr, nullptr, nullptr, nullptr, nullptr, nullptr,
                                 nullptr, flags, d_out, N, E, 1);
  }
}

// Round 9
// 358.000 us; speedup vs baseline: 1.6877x; 1.6877x over previous
//
#include <hip/hip_runtime.h>
#include <hip/hip_bf16.h>
#include <math.h>

// COSGATEncoder: N=50000, E=1280000, D=64, HEADS=1. f32 in/out (runtime-detected,
// bf16 fallback), edge_index int64 (runtime-detected, int32 fallback).
// R21: LDS counting-sort binning. R20's bucket scatter failed (WRITE 93MB,
// VALU 9%): position-scattered stores to a 21MB buffer are exactly as
// line-amplified as direct scatter, + 1024 hot global counters contended.
// Density requires TEMPORAL staging: k_scat loads ~1250 edges/block into LDS,
// 64-partition histogram, ONE global atomicAdd per partition per block to
// reserve space, LDS counting sort, dense coalesced segment write-out (~10MB,
// amp~1). k_part = 64 blocks (1 per partition): scatter within a private
// 200KB csr2 window; 8 blocks/XCD -> ~1.6MB live write set < 4MB L2 ->
// write-back ~= touched lines (~7-13MB vs 79MB). Dense GEMMs in measured
// weight-resident kernels (k_prepW 14us, k_resW ~20us, R19-verified);
// k_edge thin modes 2/3. Legacy k_bin fallback tier if workspace short.
// Rest = R18-R20: 1-wave k_edge, slot-CSR, exact slow path deg>CAP,
// fp8 fhat rows, packed 4B csr entries, LDS-broadcast legacy prep.

constexpr int D = 64;
constexpr int CAP = 64;
constexpr int NPART = 64;    // radix partitions (csr2 window 12.8MB/64 = 200KB)
constexpr int EPB_MAX = 2048;  // LDS staging capacity per chunk
constexpr float NEG_SLOPE = 0.2f;
constexpr float EPS_COS = 1e-8f;
constexpr float EPS_SM = 1e-16f;

#if defined(__has_builtin)
#if __has_builtin(__builtin_amdgcn_cvt_pk_f32_fp8) && __has_builtin(__builtin_amdgcn_cvt_pk_fp8_f32)
#define HW_FP8 1
#endif
#endif

typedef float floatx2 __attribute__((ext_vector_type(2)));

__device__ __forceinline__ float wred_sum(float v) {
#pragma unroll
  for (int off = 32; off > 0; off >>= 1) v += __shfl_xor(v, off, 64);
  return v;
}
__device__ __forceinline__ float wred_max(float v) {
#pragma unroll
  for (int off = 32; off > 0; off >>= 1) v = fmaxf(v, __shfl_xor(v, off, 64));
  return v;
}
__device__ __forceinline__ float elu1(float x) { return x > 0.f ? x : __expf(x) - 1.f; }
__device__ __forceinline__ float sane(float v) {
  return (v == v && fabsf(v) < 1e30f) ? v : 0.f;
}
__device__ __forceinline__ float ldv(const void* p, size_t i, int f32) {
  return f32 ? ((const float*)p)[i]
             : __bfloat162float(((const __hip_bfloat16*)p)[i]);
}
__device__ __forceinline__ void stv(void* p, size_t i, int f32, float v) {
  if (f32) ((float*)p)[i] = v;
  else ((__hip_bfloat16*)p)[i] = __float2bfloat16(v);
}
__device__ __forceinline__ float b2f(unsigned short u) {
  return __uint_as_float(((unsigned int)u) << 16);
}
__device__ __forceinline__ void unp8(uint4 u, float* f) {
  f[0] = __uint_as_float(u.x << 16);
  f[1] = __uint_as_float(u.x & 0xffff0000u);
  f[2] = __uint_as_float(u.y << 16);
  f[3] = __uint_as_float(u.y & 0xffff0000u);
  f[4] = __uint_as_float(u.z << 16);
  f[5] = __uint_as_float(u.z & 0xffff0000u);
  f[6] = __uint_as_float(u.w << 16);
  f[7] = __uint_as_float(u.w & 0xffff0000u);
}

// ---- fp8 helpers: HW e4m3 when available, f16-msb (e5m2-like) fallback ----
__device__ __forceinline__ unsigned char enc_fp8(float v) {
#ifdef HW_FP8
  int pk = __builtin_amdgcn_cvt_pk_fp8_f32(v, v, 0, false);
  return (unsigned char)(pk & 0xFF);
#else
  _Float16 h = (_Float16)v;
  unsigned short ub;
  __builtin_memcpy(&ub, &h, 2);
  return (unsigned char)((ub + 0x80) >> 8);  // RNE-ish truncate to top byte
#endif
}
__device__ __forceinline__ void dec_fp8x8(uint2 u, float* f) {
#ifdef HW_FP8
  floatx2 a = __builtin_amdgcn_cvt_pk_f32_fp8(u.x, false);
  floatx2 b = __builtin_amdgcn_cvt_pk_f32_fp8(u.x, true);
  floatx2 c = __builtin_amdgcn_cvt_pk_f32_fp8(u.y, false);
  floatx2 d = __builtin_amdgcn_cvt_pk_f32_fp8(u.y, true);
  f[0] = a[0]; f[1] = a[1]; f[2] = b[0]; f[3] = b[1];
  f[4] = c[0]; f[5] = c[1]; f[6] = d[0]; f[7] = d[1];
#else
#pragma unroll
  for (int i = 0; i < 8; ++i) {
    unsigned int byte = (i < 4 ? (u.x >> (8 * i)) : (u.y >> (8 * (i - 4)))) & 0xFF;
    unsigned short hb = (unsigned short)(byte << 8);
    _Float16 h;
    __builtin_memcpy(&h, &hb, 2);
    f[i] = (float)h;
  }
#endif
}

// packed csr entry: bits 0..17 = src, bits 18..31 = gate quantized to 14 bits
__device__ __forceinline__ unsigned int pack_sg(int src, float g) {
  int gq = (int)(g * 16383.f + 0.5f);
  return ((unsigned int)src & 0x3FFFFu) | ((unsigned int)gq << 18);
}
__device__ __forceinline__ int upk_src(unsigned int e, int N) {
  return min((int)(e & 0x3FFFFu), N - 1);
}
__device__ __forceinline__ float upk_gate(unsigned int e) {
  return (float)(e >> 18) * (1.f / 16383.f);
}
__device__ __forceinline__ float gate_of(float w) {
  return fminf(fmaxf(1.f - 0.25f * fminf(w, 4.f), 0.f), 1.f);
}

// full fp8-row cosine dot (slow path only)
__device__ float slow_cos(const unsigned char* __restrict__ fhat, int a, int b) {
  const uint2* fa = (const uint2*)(fhat + (size_t)a * D);
  const uint2* fb = (const uint2*)(fhat + (size_t)b * D);
  float dsum = 0.f;
  for (int q = 0; q < 8; ++q) {
    float va[8], vb[8];
    dec_fp8x8(fa[q], va);
    dec_fp8x8(fb[q], vb);
#pragma unroll
    for (int i = 0; i < 8; ++i) dsum += va[i] * vb[i];
  }
  return dsum;
}

// shared prep body (legacy tiers): LDS-broadcast GEMM
__device__ __forceinline__ void prep_node(float f, int f32, int wid, int lane,
                                          const void* __restrict__ W,
                                          const void* __restrict__ att,
                                          unsigned char* __restrict__ fhat,
                                          __hip_bfloat16* __restrict__ Hmat,
                                          float* __restrict__ a_l,
                                          float* __restrict__ a_r,
                                          float* __restrict__ ls) {
  float n2 = wred_sum(f * f);
  float nrm = fmaxf(sqrtf(n2), EPS_COS);
  fhat[(size_t)wid * D + lane] = enc_fp8(f / nrm);
  ls[lane] = f;
  __syncthreads();
  float h0 = 0.f, h1 = 0.f, h2 = 0.f, h3 = 0.f;
  if (f32) {
    const float* Wf = (const float*)W;
#pragma unroll 4
    for (int k = 0; k < D; k += 4) {
      h0 += ls[k] * Wf[k * D + lane];
      h1 += ls[k + 1] * Wf[(k + 1) * D + lane];
      h2 += ls[k + 2] * Wf[(k + 2) * D + lane];
      h3 += ls[k + 3] * Wf[(k + 3) * D + lane];
    }
  } else {
    const __hip_bfloat16* Wb = (const __hip_bfloat16*)W;
#pragma unroll 4
    for (int k = 0; k < D; k += 4) {
      h0 += ls[k] * __bfloat162float(Wb[k * D + lane]);
      h1 += ls[k + 1] * __bfloat162float(Wb[(k + 1) * D + lane]);
      h2 += ls[k + 2] * __bfloat162float(Wb[(k + 2) * D + lane]);
      h3 += ls[k + 3] * __bfloat162float(Wb[(k + 3) * D + lane]);
    }
  }
  float Hc = (h0 + h1) + (h2 + h3);
  Hmat[(size_t)wid * D + lane] = __float2bfloat16(Hc);
  float al = wred_sum(Hc * ldv(att, lane, f32));
  float ar = wred_sum(Hc * ldv(att, D + lane, f32));
  if (lane == 0) {
    a_l[wid] = al;
    a_r[wid] = ar;
  }
  __syncthreads();
}

// ---------------- R21 pass A: LDS counting-sort edge scatter ----------------
// Each block: load edge chunk to LDS, 64-part histogram, reserve global space
// (1 atomicAdd/partition), LDS sort by partition, dense coalesced write-out.
__global__ void __launch_bounds__(256) k_scat(const unsigned short* __restrict__ xu,
                                              const int* __restrict__ ei,
                                              const void* __restrict__ w,
                                              int* __restrict__ flags,
                                              int* __restrict__ cnt,
                                              int* __restrict__ pcnt,
                                              uint2* __restrict__ part, int pcap,
                                              unsigned int* __restrict__ csr2,
                                              int N, int E, int GB) {
  __shared__ uint2 buf[EPB_MAX];
  __shared__ uint2 srt[EPB_MAX];
  __shared__ int hist[NPART], hoff[NPART], hcur[NPART], gbase[NPART];
  __shared__ int sf[2];
  const int tid = threadIdx.x;
  if (tid < 64) {
    float v = b2f(xu[tid]);
    float a = fabsf(v);
    unsigned long long m = __ballot(a > 1e-4f && a < 100.f);
    unsigned long long m2 = __ballot(ei[2 * tid + 1] != 0);
    if (tid == 0) {
      sf[0] = (__popcll(m) >= 60) ? 0 : 1;  // 1 => f32
      sf[1] = (m2 == 0ull) ? 1 : 0;         // 1 => int64
      if (blockIdx.x == 0) {
        flags[0] = sf[0];
        flags[1] = sf[1];
      }
    }
  }
  __syncthreads();
  const int f32 = sf[0], wide = sf[1];
  const long long E0 = ((long long)blockIdx.x * E) / GB;
  const long long E1 = ((long long)(blockIdx.x + 1) * E) / GB;
  for (long long c0 = E0; c0 < E1; c0 += EPB_MAX) {
    const int n = (int)min((long long)EPB_MAX, E1 - c0);
    for (int i = tid; i < NPART; i += 256) hist[i] = 0;
    __syncthreads();
    // load + classify
    for (int i = tid; i < n; i += 256) {
      const long long e = c0 + i;
      int ss, dd;
      if (wide) {
        ss = ei[2 * e];
        dd = ei[2 * (size_t)E + 2 * e];
      } else {
        ss = ei[e];
        dd = ei[(size_t)E + e];
      }
      float we = ldv(w, (size_t)e, f32);
      const int dc = min(max(dd, 0), N - 1);
      const unsigned sg = pack_sg(min(max(ss, 0), N - 1), gate_of(we));
      buf[i] = make_uint2(sg, (unsigned)dc);
      atomicAdd(&hist[(int)(((long long)dc * NPART) / N)], 1);
    }
    __syncthreads();
    if (tid == 0) {
      int acc = 0;
      for (int p = 0; p < NPART; ++p) {
        hoff[p] = acc;
        hcur[p] = acc;
        acc += hist[p];
      }
    }
    __syncthreads();
    if (tid < NPART) gbase[tid] = atomicAdd(&pcnt[tid], hist[tid]);
    __syncthreads();
    // LDS counting sort
    for (int i = tid; i < n; i += 256) {
      uint2 en = buf[i];
      const int p = (int)(((long long)en.y * NPART) / N);
      const int pos = atomicAdd(&hcur[p], 1);
      srt[pos] = en;
    }
    __syncthreads();
    // dense write-out (consecutive i mostly same partition -> coalesced)
    for (int i = tid; i < n; i += 256) {
      uint2 en = srt[i];
      const int p = (int)(((long long)en.y * NPART) / N);
      const int idx = gbase[p] + (i - hoff[p]);
      if (idx < pcap) {
        part[(size_t)p * pcap + idx] = en;
      } else {  // overflow (adversarial skew): direct scatter, correct but slow
        const int slot = atomicAdd(&cnt[en.y], 1);
        if (slot < CAP) csr2[(size_t)en.y * CAP + slot] = en.x;
      }
    }
    __syncthreads();
  }
}

// ---------------- R21 pass B: partition -> csr2 (private L2-hot window) ----------------
// grid = NPART blocks, 1024 threads: ~8 blocks/XCD -> per-XCD write set ~1.6MB.
__global__ void __launch_bounds__(1024) k_part(const int* __restrict__ pcnt,
                                               const uint2* __restrict__ part, int pcap,
                                               int* __restrict__ cnt,
                                               unsigned int* __restrict__ csr2, int N) {
  const int p = blockIdx.x;
  const int np = min(pcnt[p], pcap);
  const uint2* base = part + (size_t)p * pcap;
  for (int i = threadIdx.x; i < np; i += 1024) {
    uint2 en = base[i];
    const int dc = min((int)en.y, N - 1);
    const int slot = atomicAdd(&cnt[dc], 1);
    if (slot < CAP) csr2[(size_t)dc * CAP + slot] = en.x;
  }
}

// ---------------- legacy binning kernel (fallback tiers) ----------------
__global__ void __launch_bounds__(256) k_bin(const unsigned short* __restrict__ xu,
                                             const int* __restrict__ ei,
                                             const void* __restrict__ w,
                                             int* __restrict__ flags,
                                             int* __restrict__ cnt,
                                             unsigned int* __restrict__ csr2,
                                             int N, int E) {
  __shared__ int sf[2];
  const int tid = threadIdx.x;
  if (tid < 64) {
    float v = b2f(xu[tid]);
    float a = fabsf(v);
    unsigned long long m = __ballot(a > 1e-4f && a < 100.f);
    unsigned long long m2 = __ballot(ei[2 * tid + 1] != 0);
    if (tid == 0) {
      sf[0] = (__popcll(m) >= 60) ? 0 : 1;
      sf[1] = (m2 == 0ull) ? 1 : 0;
      if (blockIdx.x == 0) {
        flags[0] = sf[0];
        flags[1] = sf[1];
      }
    }
  }
  __syncthreads();
  const int f32 = sf[0], wide = sf[1];
  const int e0 = (blockIdx.x * 256 + tid) * 2;
  if (e0 >= E) return;
  const bool has1 = (e0 + 1 < E);
  int s0, s1, d0, d1;
  if (wide) {
    int4 vs = *(const int4*)(ei + 2 * (size_t)e0);
    int4 vd = *(const int4*)(ei + 2 * (size_t)E + 2 * (size_t)e0);
    s0 = vs.x; s1 = vs.z; d0 = vd.x; d1 = vd.z;
  } else {
    int2 vs = *(const int2*)(ei + e0);
    int2 vd = *(const int2*)(ei + (size_t)E + e0);
    s0 = vs.x; s1 = vs.y; d0 = vd.x; d1 = vd.y;
  }
  float w0, w1 = 0.f;
  if (f32) {
    float2 wv = *(const float2*)((const float*)w + e0);
    w0 = wv.x; w1 = wv.y;
  } else {
    const __hip_bfloat16* wb = (const __hip_bfloat16*)w;
    w0 = __bfloat162float(wb[e0]);
    if (has1) w1 = __bfloat162float(wb[e0 + 1]);
  }
  int d0c = min(max(d0, 0), N - 1);
  int slot0 = atomicAdd(&cnt[d0c], 1);
  if (slot0 < CAP)
    csr2[(size_t)d0c * CAP + slot0] = pack_sg(min(max(s0, 0), N - 1), gate_of(w0));
  if (has1) {
    int d1c = min(max(d1, 0), N - 1);
    int slot1 = atomicAdd(&cnt[d1c], 1);
    if (slot1 < CAP)
      csr2[(size_t)d1c * CAP + slot1] = pack_sg(min(max(s1, 0), N - 1), gate_of(w1));
  }
}

// ---------------- weight-resident node prep (grid-stride) ----------------
__global__ void __launch_bounds__(64, 4) k_prepW(const void* __restrict__ xin,
                                                 const void* __restrict__ W,
                                                 const void* __restrict__ att,
                                                 const int* __restrict__ flags,
                                                 unsigned char* __restrict__ fhat,
                                                 __hip_bfloat16* __restrict__ Hmat,
                                                 float* __restrict__ a_l,
                                                 float* __restrict__ a_r, int N) {
  __shared__ float ls[D];
  const int lane = threadIdx.x;
  const int f32 = flags[0];
  float wreg[D];
  if (f32) {
    const float* Wf = (const float*)W;
#pragma unroll
    for (int k = 0; k < D; ++k) wreg[k] = Wf[k * D + lane];
  } else {
    const __hip_bfloat16* Wb = (const __hip_bfloat16*)W;
#pragma unroll
    for (int k = 0; k < D; ++k) wreg[k] = __bfloat162float(Wb[k * D + lane]);
  }
  const float attl = ldv(att, lane, f32);
  const float attr = ldv(att, D + lane, f32);
  float f = (blockIdx.x < (unsigned)N) ? ldv(xin, (size_t)blockIdx.x * D + lane, f32) : 0.f;
  for (int wid = blockIdx.x; wid < N; wid += gridDim.x) {
    const int nwid = wid + gridDim.x;
    float fnx = (nwid < N) ? ldv(xin, (size_t)nwid * D + lane, f32) : 0.f;  // prefetch
    float n2 = wred_sum(f * f);
    float nrm = fmaxf(sqrtf(n2), EPS_COS);
    fhat[(size_t)wid * D + lane] = enc_fp8(f / nrm);
    ls[lane] = f;
    __syncthreads();
    float h0 = 0.f, h1 = 0.f, h2 = 0.f, h3 = 0.f;
#pragma unroll
    for (int k = 0; k < D; k += 4) {
      h0 += ls[k] * wreg[k];
      h1 += ls[k + 1] * wreg[k + 1];
      h2 += ls[k + 2] * wreg[k + 2];
      h3 += ls[k + 3] * wreg[k + 3];
    }
    float Hc = (h0 + h1) + (h2 + h3);
    Hmat[(size_t)wid * D + lane] = __float2bfloat16(Hc);
    float al = wred_sum(Hc * attl);
    float ar = wred_sum(Hc * attr);
    if (lane == 0) {
      a_l[wid] = al;
      a_r[wid] = ar;
    }
    __syncthreads();
    f = fnx;
  }
}

// ---------------- weight-resident residual MLP (grid-stride) ----------------
__global__ void __launch_bounds__(64, 3) k_resW(const void* __restrict__ xin,
                                                const void* __restrict__ rW1,
                                                const void* __restrict__ rb1,
                                                const void* __restrict__ rW2,
                                                const void* __restrict__ rb2,
                                                const int* __restrict__ flags,
                                                float* __restrict__ xres, int N) {
  __shared__ float ls[D];
  const int lane = threadIdx.x;
  const int f32 = flags[0];
  float w1reg[D], w2reg[D];
  if (f32) {
    const float* w1 = (const float*)rW1;
    const float* w2 = (const float*)rW2;
#pragma unroll
    for (int k = 0; k < D; ++k) w1reg[k] = w1[k * D + lane];
#pragma unroll
    for (int k = 0; k < D; ++k) w2reg[k] = w2[k * D + lane];
  } else {
    const __hip_bfloat16* w1 = (const __hip_bfloat16*)rW1;
    const __hip_bfloat16* w2 = (const __hip_bfloat16*)rW2;
#pragma unroll
    for (int k = 0; k < D; ++k) w1reg[k] = __bfloat162float(w1[k * D + lane]);
#pragma unroll
    for (int k = 0; k < D; ++k) w2reg[k] = __bfloat162float(w2[k * D + lane]);
  }
  const float b1v = ldv(rb1, lane, f32);
  const float b2v = ldv(rb2, lane, f32);
  float f = (blockIdx.x < (unsigned)N) ? ldv(xin, (size_t)blockIdx.x * D + lane, f32) : 0.f;
  for (int wid = blockIdx.x; wid < N; wid += gridDim.x) {
    const int nwid = wid + gridDim.x;
    float fnx = (nwid < N) ? ldv(xin, (size_t)nwid * D + lane, f32) : 0.f;  // prefetch
    ls[lane] = f;
    __syncthreads();
    float h0 = b1v, h1 = 0.f, h2 = 0.f, h3 = 0.f;
#pragma unroll
    for (int k = 0; k < D; k += 4) {
      h0 += ls[k] * w1reg[k];
      h1 += ls[k + 1] * w1reg[k + 1];
      h2 += ls[k + 2] * w1reg[k + 2];
      h3 += ls[k + 3] * w1reg[k + 3];
    }
    float tr = fmaxf((h0 + h1) + (h2 + h3), 0.f);
    __syncthreads();
    ls[lane] = tr;
    __syncthreads();
    float g0 = b2v, g1 = 0.f, g2 = 0.f, g3 = 0.f;
#pragma unroll
    for (int k = 0; k < D; k += 4) {
      g0 += ls[k] * w2reg[k];
      g1 += ls[k + 1] * w2reg[k + 1];
      g2 += ls[k + 2] * w2reg[k + 2];
      g3 += ls[k + 3] * w2reg[k + 3];
    }
    xres[(size_t)wid * D + lane] = (g0 + g1) + (g2 + g3);
    __syncthreads();
    f = fnx;
  }
}

// standalone prep (legacy non-fused tier) — 64-thread, grid=N
__global__ void __launch_bounds__(64) k_prep(const void* __restrict__ xin,
                                             const void* __restrict__ W,
                                             const void* __restrict__ att,
                                             const int* __restrict__ flags,
                                             unsigned char* __restrict__ fhat,
                                             __hip_bfloat16* __restrict__ Hmat,
                                             float* __restrict__ a_l,
                                             float* __restrict__ a_r, int N) {
  __shared__ float ls[D];
  const int lane = threadIdx.x;
  const int wid = blockIdx.x;
  if (wid >= N) return;
  const int f32 = flags[0];
  float f = ldv(xin, (size_t)wid * D + lane, f32);
  prep_node(f, f32, wid, lane, W, att, fhat, Hmat, a_l, a_r, ls);
}

// ---------------- edge kernel: ONE wave per dst node (64-thread blocks) ----------------
// modes: 0=prep epilogue (legacy), 1=in-kernel MLP (legacy), 2=store double-elu,
//        3=v + xres -> out (main path)
__global__ void __launch_bounds__(64, 8) k_edge(const int* __restrict__ cnt,
                                                const unsigned int* __restrict__ csr2,
                                                const int* __restrict__ ei,
                                                const void* __restrict__ w,
                                                const unsigned char* __restrict__ fhat,
                                                const __hip_bfloat16* __restrict__ Hmat,
                                                const float* __restrict__ a_l,
                                                const float* __restrict__ a_r,
                                                const void* __restrict__ beta,
                                                const void* __restrict__ bias,
                                                const void* __restrict__ x,
                                                const void* __restrict__ rW1,
                                                const void* __restrict__ rb1,
                                                const void* __restrict__ rW2,
                                                const void* __restrict__ rb2,
                                                const void* __restrict__ Wn,
                                                const void* __restrict__ attn,
                                                unsigned char* __restrict__ fh2,
                                                __hip_bfloat16* __restrict__ Hm2,
                                                float* __restrict__ al2,
                                                float* __restrict__ ar2,
                                                const float* __restrict__ xres,
                                                const int* __restrict__ flags,
                                                void* __restrict__ out,
                                                int N, int E, int mode) {
  const int lane = threadIdx.x;
  const int wid = blockIdx.x;
  __shared__ float2 lc[CAP];  // (l, c) per edge
  __shared__ float2 sg[CAP];  // (src bits, p) — written in phase 2
  __shared__ float lds_t[D];  // acc transpose; reused as GEMM staging in epilogue
  if (wid >= N) return;
  const int f32 = flags[0];
  const int g = lane >> 3;   // edge slot in 8-edge group
  const int sub = lane & 7;  // feature block: [8*sub, 8*sub+8)
  const int degRaw = cnt[wid];
  const float aln = a_l[wid];
  const float bb = 1.f / (1.f + __expf(-ldv(beta, 0, f32)));
  const float ob = 1.f - bb;
  const char* HmatB = (const char*)Hmat;

  float v;  // pre-elu output feature for this lane
  if (degRaw <= CAP) {
    // ================= fast path (always taken on bench data) =================
    const int deg = degRaw;
    const int s = wid * CAP;
    float fn[8];
    dec_fp8x8(*(const uint2*)(fhat + (((unsigned)wid << 6) | ((unsigned)sub << 3))), fn);

    // ---- phase 1 (iters 0-3, static): fp8 gathers + Hmat prefetch to regs ----
    float m1 = -1e30f, m2 = -1e30f;
    uint4 hm[4];
#pragma unroll
    for (int kk = 0; kk < 4; ++kk) {
      const int base = kk * 8;
      if (base < deg) {
        const int j = base + g;
        const bool val = j < deg;
        const unsigned int en = val ? csr2[s + j] : (unsigned int)wid;
        const unsigned src = (unsigned)upk_src(en, N);
        float hv[8];
        dec_fp8x8(*(const uint2*)(fhat + ((src << 6) | ((unsigned)sub << 3))), hv);
        hm[kk] = *(const uint4*)(HmatB + ((src << 7) | ((unsigned)sub << 4)));
        float d = 0.f;
#pragma unroll
        for (int i = 0; i < 8; ++i) d += fn[i] * hv[i];
        d += __shfl_xor(d, 1, 64);
        d += __shfl_xor(d, 2, 64);
        d += __shfl_xor(d, 4, 64);
        float l = aln + a_r[src];
        l = (l >= 0.f) ? l : NEG_SLOPE * l;
        if (val) {
          m1 = fmaxf(m1, l);
          m2 = fmaxf(m2, d);
          if (sub == 0) lc[j] = make_float2(l, d);
        }
      }
    }
    // tail iterations (deg > 32): no prefetch
    for (int base = 32; base < deg; base += 8) {
      const int j = base + g;
      const bool val = j < deg;
      const unsigned int en = val ? csr2[s + j] : (unsigned int)wid;
      const unsigned src = (unsigned)upk_src(en, N);
      float hv[8];
      dec_fp8x8(*(const uint2*)(fhat + ((src << 6) | ((unsigned)sub << 3))), hv);
      float d = 0.f;
#pragma unroll
      for (int i = 0; i < 8; ++i) d += fn[i] * hv[i];
      d += __shfl_xor(d, 1, 64);
      d += __shfl_xor(d, 2, 64);
      d += __shfl_xor(d, 4, 64);
      float l = aln + a_r[src];
      l = (l >= 0.f) ? l : NEG_SLOPE * l;
      if (val) {
        m1 = fmaxf(m1, l);
        m2 = fmaxf(m2, d);
        if (sub == 0) lc[j] = make_float2(l, d);
      }
    }
    m1 = fmaxf(m1, __shfl_xor(m1, 8, 64));
    m1 = fmaxf(m1, __shfl_xor(m1, 16, 64));
    m1 = fmaxf(m1, __shfl_xor(m1, 32, 64));
    m2 = fmaxf(m2, __shfl_xor(m2, 8, 64));
    m2 = fmaxf(m2, __shfl_xor(m2, 16, 64));
    m2 = fmaxf(m2, __shfl_xor(m2, 32, 64));

    // ---- phase 2: dual softmax sums + fused p (deg <= 64 always) ----
    float el0 = 0.f, ec0 = 0.f, gg0 = 0.f;
    int q0 = 0;
    float ps1 = 0.f, ps2 = 0.f;
    if (lane < deg) {
      const unsigned int en = csr2[s + lane];  // coalesced, L2-hot
      q0 = upk_src(en, N);
      gg0 = upk_gate(en);
      float2 t = lc[lane];
      el0 = __expf(t.x - m1);
      ec0 = __expf(t.y - m2);
      ps1 = el0;
      ps2 = ec0;
    }
    const float rs1 = 1.f / (wred_sum(ps1) + EPS_SM);
    const float rs2 = 1.f / (wred_sum(ps2) + EPS_SM);

    float sp = 0.f;
    if (lane < deg) {
      float tt = (ob * el0 * rs1 + bb * ec0 * rs2) * gg0;
      float p0 = __expf(tt - 1.f);
      sp = p0;
      sg[lane] = make_float2(__int_as_float(q0), p0);  // (src, p)
    }
    const float rinv = 1.f / (wred_sum(sp) + EPS_SM);

    // ---- phase 3: register-resident Hmat for iters 0-3; gathers for tail ----
    float acc[8] = {0.f, 0.f, 0.f, 0.f, 0.f, 0.f, 0.f, 0.f};
#pragma unroll
    for (int kk = 0; kk < 4; ++kk) {
      const int base = kk * 8;
      if (base < deg) {
        const int j = base + g;
        const float pv = (j < deg) ? sg[j].y : 0.f;
        float hv[8];
        unp8(hm[kk], hv);
#pragma unroll
        for (int i = 0; i < 8; ++i) acc[i] += pv * hv[i];
      }
    }
    for (int base = 32; base < deg; base += 8) {
      const int j = base + g;
      float2 en = (j < deg) ? sg[j] : make_float2(__int_as_float(wid), 0.f);
      const float pv = en.y;
      const unsigned srcv = (unsigned)__float_as_int(en.x);
      float hv[8];
      unp8(*(const uint4*)(HmatB + ((srcv << 7) | ((unsigned)sub << 4))), hv);
#pragma unroll
      for (int i = 0; i < 8; ++i) acc[i] += pv * hv[i];
    }
#pragma unroll
    for (int i = 0; i < 8; ++i) {
      acc[i] += __shfl_xor(acc[i], 8, 64);
      acc[i] += __shfl_xor(acc[i], 16, 64);
      acc[i] += __shfl_xor(acc[i], 32, 64);
    }
    if (g == 0) {
#pragma unroll
      for (int i = 0; i < 8; ++i) lds_t[8 * sub + i] = acc[i];
    }
    v = lds_t[lane] * rinv + ldv(bias, lane, f32);
  } else {
    // ============ slow path: exact 3-pass over raw edge list ============
    const int wide = flags[1];
    lds_t[lane] = 0.f;
    float m1 = -1e30f, m2 = -1e30f;
    for (int e64 = lane; e64 < E; e64 += 64) {
      int dd = wide ? ei[2 * (size_t)E + 2 * (size_t)e64] : ei[(size_t)E + e64];
      if (dd != wid) continue;
      int ss = wide ? ei[2 * (size_t)e64] : ei[e64];
      ss = min(max(ss, 0), N - 1);
      float l = aln + a_r[ss];
      l = (l >= 0.f) ? l : NEG_SLOPE * l;
      float c = slow_cos(fhat, wid, ss);
      m1 = fmaxf(m1, l);
      m2 = fmaxf(m2, c);
    }
    m1 = wred_max(m1);
    m2 = wred_max(m2);
    float ps1 = 0.f, ps2 = 0.f;
    for (int e64 = lane; e64 < E; e64 += 64) {
      int dd = wide ? ei[2 * (size_t)E + 2 * (size_t)e64] : ei[(size_t)E + e64];
      if (dd != wid) continue;
      int ss = wide ? ei[2 * (size_t)e64] : ei[e64];
      ss = min(max(ss, 0), N - 1);
      float l = aln + a_r[ss];
      l = (l >= 0.f) ? l : NEG_SLOPE * l;
      float c = slow_cos(fhat, wid, ss);
      ps1 += __expf(l - m1);
      ps2 += __expf(c - m2);
    }
    const float rs1 = 1.f / (wred_sum(ps1) + EPS_SM);
    const float rs2 = 1.f / (wred_sum(ps2) + EPS_SM);
    float sp = 0.f;
    for (int e64 = lane; e64 < E; e64 += 64) {
      int dd = wide ? ei[2 * (size_t)E + 2 * (size_t)e64] : ei[(size_t)E + e64];
      if (dd != wid) continue;
      int ss = wide ? ei[2 * (size_t)e64] : ei[e64];
      ss = min(max(ss, 0), N - 1);
      float l = aln + a_r[ss];
      l = (l >= 0.f) ? l : NEG_SLOPE * l;
      float c = slow_cos(fhat, wid, ss);
      float gx = gate_of(ldv(w, e64, f32));
      float px = __expf((ob * __expf(l - m1) * rs1 + bb * __expf(c - m2) * rs2) * gx - 1.f);
      sp += px;
      for (int q = 0; q < D; ++q)
        atomicAdd(&lds_t[q], px * __bfloat162float(Hmat[(size_t)ss * D + q]));
    }
    const float rinv = 1.f / (wred_sum(sp) + EPS_SM);
    v = lds_t[lane] * rinv + ldv(bias, lane, f32);
  }

  v = elu1(v);  // elu inside _cosgat
  if (mode == 3) {
    float a2 = xres[(size_t)wid * D + lane];
    stv(out, (size_t)wid * D + lane, f32, sane(v + a2));
  } else if (mode == 1) {
    // legacy: fused residual MLP — LDS-broadcast GEMMs
    float xv = ldv(x, (size_t)wid * D + lane, f32);
    float b0_ = ldv(rb1, lane, f32);
    __syncthreads();
    lds_t[lane] = xv;
    __syncthreads();
    float a2;
    float h0 = 0.f, h1 = 0.f, h2 = 0.f, h3 = 0.f;
    if (f32) {
      const float* w1 = (const float*)rW1;
      const float* w2 = (const float*)rW2;
#pragma unroll 4
      for (int k = 0; k < D; k += 4) {
        h0 += lds_t[k] * w1[k * D + lane];
        h1 += lds_t[k + 1] * w1[(k + 1) * D + lane];
        h2 += lds_t[k + 2] * w1[(k + 2) * D + lane];
        h3 += lds_t[k + 3] * w1[(k + 3) * D + lane];
      }
      float tr = fmaxf(b0_ + (h0 + h1) + (h2 + h3), 0.f);
      __syncthreads();
      lds_t[lane] = tr;
      __syncthreads();
      float g0 = 0.f, g1 = 0.f, g2 = 0.f, g3 = 0.f;
#pragma unroll 4
      for (int k = 0; k < D; k += 4) {
        g0 += lds_t[k] * w2[k * D + lane];
        g1 += lds_t[k + 1] * w2[(k + 1) * D + lane];
        g2 += lds_t[k + 2] * w2[(k + 2) * D + lane];
        g3 += lds_t[k + 3] * w2[(k + 3) * D + lane];
      }
      a2 = ((const float*)rb2)[lane] + (g0 + g1) + (g2 + g3);
    } else {
      const __hip_bfloat16* w1 = (const __hip_bfloat16*)rW1;
      const __hip_bfloat16* w2 = (const __hip_bfloat16*)rW2;
#pragma unroll 4
      for (int k = 0; k < D; k += 4) {
        h0 += lds_t[k] * __bfloat162float(w1[k * D + lane]);
        h1 += lds_t[k + 1] * __bfloat162float(w1[(k + 1) * D + lane]);
        h2 += lds_t[k + 2] * __bfloat162float(w1[(k + 2) * D + lane]);
        h3 += lds_t[k + 3] * __bfloat162float(w1[(k + 3) * D + lane]);
      }
      float tr = fmaxf(b0_ + (h0 + h1) + (h2 + h3), 0.f);
      __syncthreads();
      lds_t[lane] = tr;
      __syncthreads();
      float g0 = 0.f, g1 = 0.f, g2 = 0.f, g3 = 0.f;
#pragma unroll 4
      for (int k = 0; k < D; k += 4) {
        g0 += lds_t[k] * __bfloat162float(w2[k * D + lane]);
        g1 += lds_t[k + 1] * __bfloat162float(w2[(k + 1) * D + lane]);
        g2 += lds_t[k + 2] * __bfloat162float(w2[(k + 2) * D + lane]);
        g3 += lds_t[k + 3] * __bfloat162float(w2[(k + 3) * D + lane]);
      }
      a2 = __bfloat162float(((const __hip_bfloat16*)rb2)[lane]) + (g0 + g1) + (g2 + g3);
    }
    stv(out, (size_t)wid * D + lane, f32, sane(v + a2));
  } else {
    v = elu1(v);  // inter-layer elu
    if (mode == 0) {
      __syncthreads();
      prep_node(sane(v), f32, wid, lane, Wn, attn, fh2, Hm2, al2, ar2, lds_t);
    } else {  // mode 2: store double-elu (to hbuf or out)
      stv(out, (size_t)wid * D + lane, f32, sane(v));
    }
  }
}

extern "C" void kernel_launch(void* const* d_in, const int* in_sizes, int n_in,
                              void* d_out, int out_size, void* d_ws, size_t ws_size,
                              hipStream_t stream) {
  const void* x = d_in[0];
  const int* ei = (const int*)d_in[1];
  const void* w = d_in[2];
  const void* W0 = d_in[3];
  const void* att0 = d_in[4];
  const void* beta0 = d_in[5];
  const void* b0 = d_in[6];
  const void* W1 = d_in[7];
  const void* att1 = d_in[8];
  const void* beta1 = d_in[9];
  const void* b1 = d_in[10];
  const void* rW1 = d_in[11];
  const void* rb1 = d_in[12];
  const void* rW2 = d_in[13];
  const void* rb2 = d_in[14];

  const int N = in_sizes[0] / D;
  const int E = in_sizes[2];

  char* base = (char*)d_ws;
  size_t off = 0;
  auto alloc = [&](size_t bytes) -> void* {
    void* p = base + off;
    off += (bytes + 255) & ~(size_t)255;
    return p;
  };
  // common tier
  int* flags = (int*)alloc(256);
  int* cnt = (int*)alloc((size_t)N * 4);
  unsigned int* csr2 = (unsigned int*)alloc((size_t)N * CAP * 4);
  unsigned char* fhat = (unsigned char*)alloc((size_t)N * D);
  __hip_bfloat16* Hmat = (__hip_bfloat16*)alloc((size_t)N * D * 2);
  float* a_l = (float*)alloc((size_t)N * 4);
  float* a_r = (float*)alloc((size_t)N * 4);
  const size_t common_off = off;
  // tier R (radix): hbuf + xres + pcnt + part
  float* hbuf = (float*)alloc((size_t)N * D * 4);
  float* xres = (float*)alloc((size_t)N * D * 4);
  int* pcnt = (int*)alloc((size_t)NPART * 4);
  const int pcap = E / NPART + E / (NPART * 8) + 512;
  uint2* part = (uint2*)alloc((size_t)NPART * (size_t)pcap * 8);
  const bool tierR = (off <= ws_size);
  // tier A (R19-style, no part buffer): hbuf + xres only
  off = common_off;
  float* hbufA = (float*)alloc((size_t)N * D * 4);
  float* xresA = (float*)alloc((size_t)N * D * 4);
  const bool tierA = (off <= ws_size);
  // tier B (legacy fused): second-layer prep buffers (alias region)
  off = common_off;
  unsigned char* fhat2 = (unsigned char*)alloc((size_t)N * D);
  __hip_bfloat16* Hmat2 = (__hip_bfloat16*)alloc((size_t)N * D * 2);
  float* a_l2 = (float*)alloc((size_t)N * 4);
  float* a_r2 = (float*)alloc((size_t)N * 4);
  const bool tierB = (off <= ws_size);

  const int eb2 = (E / 2 + 255) / 256;
  const int GB = 1024;  // k_scat blocks

  hipMemsetAsync(cnt, 0, (size_t)N * 4, stream);

  if (tierR) {
    hipMemsetAsync(pcnt, 0, (size_t)NPART * 4, stream);
    k_scat<<<GB, 256, 0, stream>>>((const unsigned short*)x, ei, w, flags, cnt,
                                   pcnt, part, pcap, csr2, N, E, GB);
    k_part<<<NPART, 1024, 0, stream>>>(pcnt, part, pcap, cnt, csr2, N);
    k_prepW<<<4096, 64, 0, stream>>>(x, W0, att0, flags, fhat, Hmat, a_l, a_r, N);
    k_resW<<<3072, 64, 0, stream>>>(x, rW1, rb1, rW2, rb2, flags, xres, N);
    k_edge<<<N, 64, 0, stream>>>(cnt, csr2, ei, w, fhat, Hmat, a_l, a_r,
                                 beta0, b0, x, rW1, rb1, rW2, rb2,
                                 nullptr, nullptr, nullptr, nullptr, nullptr, nullptr,
                                 nullptr, flags, hbuf, N, E, 2);
    k_prepW<<<4096, 64, 0, stream>>>(hbuf, W1, att1, flags, fhat, Hmat, a_l, a_r, N);
    k_edge<<<N, 64, 0, stream>>>(cnt, csr2, ei, w, fhat, Hmat, a_l, a_r,
                                 beta1, b1, x, rW1, rb1, rW2, rb2,
                                 nullptr, nullptr, nullptr, nullptr, nullptr, nullptr,
                                 xres, flags, d_out, N, E, 3);
  } else if (tierA) {
    k_bin<<<eb2, 256, 0, stream>>>((const unsigned short*)x, ei, w, flags, cnt,
                                   csr2, N, E);
    k_prepW<<<4096, 64, 0, stream>>>(x, W0, att0, flags, fhat, Hmat, a_l, a_r, N);
    k_resW<<<3072, 64, 0, stream>>>(x, rW1, rb1, rW2, rb2, flags, xresA, N);
    k_edge<<<N, 64, 0, stream>>>(cnt, csr2, ei, w, fhat, Hmat, a_l, a_r,
                                 beta0, b0, x, rW1, rb1, rW2, rb2,
                                 nullptr, nullptr, nullptr, nullptr, nullptr, nullptr,
                                 nullptr, flags, hbufA, N, E, 2);
    k_prepW<<<4096, 64, 0, stream>>>(hbufA, W1, att1, flags, fhat, Hmat, a_l, a_r, N);
    k_edge<<<N, 64, 0, stream>>>(cnt, csr2, ei, w, fhat, Hmat, a_l, a_r,
                                 beta1, b1, x, rW1, rb1, rW2, rb2,
                                 nullptr, nullptr, nullptr, nullptr, nullptr, nullptr,
                                 xresA, flags, d_out, N, E, 3);
  } else if (tierB) {
    k_bin<<<eb2, 256, 0, stream>>>((const unsigned short*)x, ei, w, flags, cnt,
                                   csr2, N, E);
    k_prep<<<N, 64, 0, stream>>>(x, W0, att0, flags, fhat, Hmat, a_l, a_r, N);
    k_edge<<<N, 64, 0, stream>>>(cnt, csr2, ei, w, fhat, Hmat, a_l, a_r,
                                 beta0, b0, x, rW1, rb1, rW2, rb2,
                                 W1, att1, fhat2, Hmat2, a_l2, a_r2,
                                 nullptr, flags, d_out, N, E, 0);
    k_edge<<<N, 64, 0, stream>>>(cnt, csr2, ei, w, fhat2, Hmat2, a_l2, a_r2,
                                 beta1, b1, x, rW1, rb1, rW2, rb2,
                                 nullptr, nullptr, nullptr, nullptr, nullptr, nullptr,
                                 nullptr, flags, d_out, N, E, 1);
  } else {
    k_bin<<<eb2, 256, 0, stream>>>((const unsigned short*)x, ei, w, flags, cnt,
                                   csr2, N, E);
    k_prep<<<N, 64, 0, stream>>>(x, W0, att0, flags, fhat, Hmat, a_l, a_r, N);
    k_edge<<<N, 64, 0, stream>>>(cnt, csr2, ei, w, fhat, Hmat, a_l, a_r,
                                 beta0, b0, x, rW1, rb1, rW2, rb2,
                                 nullptr, nullptr, nullptr, nullptr, nullptr, nullptr,
                                 nullptr, flags, d_out, N, E, 2);
    k_prep<<<N, 64, 0, stream>>>(d_out, W1, att1, flags, fhat, Hmat, a_l, a_r, N);
    k_edge<<<N, 64, 0, stream>>>(cnt, csr2, ei, w, fhat, Hmat, a_l, a_r,
                                 beta1, b1, x, rW1, rb1, rW2, rb2,
                                 nullptr, nullptr, nullptr, nullptr, nullptr, nullptr,
                                 nullptr, flags, d_out, N, E, 1);
  }
}

// Round 10
// 344.382 us; speedup vs baseline: 1.7544x; 1.0395x over previous
//
#include <hip/hip_runtime.h>
#include <hip/hip_bf16.h>
#include <math.h>

// COSGATEncoder: N=50000, E=1280000, D=64, HEADS=1. f32 in/out (runtime-detected,
// bf16 fallback), edge_index int64 (runtime-detected, int32 fallback).
// R22: best-of-measured hybrid. Binning experiments (R19 k_bin 109us direct;
// R20 buckets 331us; R21 radix ~= direct) show scatter has a ~100us floor
// (write-amp + latency, VALU ~1%) and the ONLY thing that ever paid was fusing
// dense work into its stall shadow (R17/R18). So: k_all = direct scatter +
// prep0 + residual MLP (R20 body minus buckets). Back end = R21's proven thin
// path: k_edge(mode4: bf16->hbuf, 62us measured) -> k_prepW(hbuf bf16) ->
// k_edge(mode3: +xres->out, 62us). hbuf bf16 halves its traffic. 5 dispatches.
// Rest: 1-wave k_edge w/ reg-resident Hmat (deg<=32), slot-CSR, exact slow
// path deg>CAP, fp8 fhat rows, packed 4B csr, LDS-broadcast GEMMs.

constexpr int D = 64;
constexpr int CAP = 64;
constexpr float NEG_SLOPE = 0.2f;
constexpr float EPS_COS = 1e-8f;
constexpr float EPS_SM = 1e-16f;

#if defined(__has_builtin)
#if __has_builtin(__builtin_amdgcn_cvt_pk_f32_fp8) && __has_builtin(__builtin_amdgcn_cvt_pk_fp8_f32)
#define HW_FP8 1
#endif
#endif

typedef float floatx2 __attribute__((ext_vector_type(2)));

__device__ __forceinline__ float wred_sum(float v) {
#pragma unroll
  for (int off = 32; off > 0; off >>= 1) v += __shfl_xor(v, off, 64);
  return v;
}
__device__ __forceinline__ float wred_max(float v) {
#pragma unroll
  for (int off = 32; off > 0; off >>= 1) v = fmaxf(v, __shfl_xor(v, off, 64));
  return v;
}
__device__ __forceinline__ float elu1(float x) { return x > 0.f ? x : __expf(x) - 1.f; }
__device__ __forceinline__ float sane(float v) {
  return (v == v && fabsf(v) < 1e30f) ? v : 0.f;
}
__device__ __forceinline__ float ldv(const void* p, size_t i, int f32) {
  return f32 ? ((const float*)p)[i]
             : __bfloat162float(((const __hip_bfloat16*)p)[i]);
}
__device__ __forceinline__ void stv(void* p, size_t i, int f32, float v) {
  if (f32) ((float*)p)[i] = v;
  else ((__hip_bfloat16*)p)[i] = __float2bfloat16(v);
}
__device__ __forceinline__ float b2f(unsigned short u) {
  return __uint_as_float(((unsigned int)u) << 16);
}
__device__ __forceinline__ void unp8(uint4 u, float* f) {
  f[0] = __uint_as_float(u.x << 16);
  f[1] = __uint_as_float(u.x & 0xffff0000u);
  f[2] = __uint_as_float(u.y << 16);
  f[3] = __uint_as_float(u.y & 0xffff0000u);
  f[4] = __uint_as_float(u.z << 16);
  f[5] = __uint_as_float(u.z & 0xffff0000u);
  f[6] = __uint_as_float(u.w << 16);
  f[7] = __uint_as_float(u.w & 0xffff0000u);
}

// ---- fp8 helpers: HW e4m3 when available, f16-msb (e5m2-like) fallback ----
__device__ __forceinline__ unsigned char enc_fp8(float v) {
#ifdef HW_FP8
  int pk = __builtin_amdgcn_cvt_pk_fp8_f32(v, v, 0, false);
  return (unsigned char)(pk & 0xFF);
#else
  _Float16 h = (_Float16)v;
  unsigned short ub;
  __builtin_memcpy(&ub, &h, 2);
  return (unsigned char)((ub + 0x80) >> 8);  // RNE-ish truncate to top byte
#endif
}
__device__ __forceinline__ void dec_fp8x8(uint2 u, float* f) {
#ifdef HW_FP8
  floatx2 a = __builtin_amdgcn_cvt_pk_f32_fp8(u.x, false);
  floatx2 b = __builtin_amdgcn_cvt_pk_f32_fp8(u.x, true);
  floatx2 c = __builtin_amdgcn_cvt_pk_f32_fp8(u.y, false);
  floatx2 d = __builtin_amdgcn_cvt_pk_f32_fp8(u.y, true);
  f[0] = a[0]; f[1] = a[1]; f[2] = b[0]; f[3] = b[1];
  f[4] = c[0]; f[5] = c[1]; f[6] = d[0]; f[7] = d[1];
#else
#pragma unroll
  for (int i = 0; i < 8; ++i) {
    unsigned int byte = (i < 4 ? (u.x >> (8 * i)) : (u.y >> (8 * (i - 4)))) & 0xFF;
    unsigned short hb = (unsigned short)(byte << 8);
    _Float16 h;
    __builtin_memcpy(&h, &hb, 2);
    f[i] = (float)h;
  }
#endif
}

// packed csr entry: bits 0..17 = src, bits 18..31 = gate quantized to 14 bits
__device__ __forceinline__ unsigned int pack_sg(int src, float g) {
  int gq = (int)(g * 16383.f + 0.5f);
  return ((unsigned int)src & 0x3FFFFu) | ((unsigned int)gq << 18);
}
__device__ __forceinline__ int upk_src(unsigned int e, int N) {
  return min((int)(e & 0x3FFFFu), N - 1);
}
__device__ __forceinline__ float upk_gate(unsigned int e) {
  return (float)(e >> 18) * (1.f / 16383.f);
}
__device__ __forceinline__ float gate_of(float w) {
  return fminf(fmaxf(1.f - 0.25f * fminf(w, 4.f), 0.f), 1.f);
}

// full fp8-row cosine dot (slow path only)
__device__ float slow_cos(const unsigned char* __restrict__ fhat, int a, int b) {
  const uint2* fa = (const uint2*)(fhat + (size_t)a * D);
  const uint2* fb = (const uint2*)(fhat + (size_t)b * D);
  float dsum = 0.f;
  for (int q = 0; q < 8; ++q) {
    float va[8], vb[8];
    dec_fp8x8(fa[q], va);
    dec_fp8x8(fb[q], vb);
#pragma unroll
    for (int i = 0; i < 8; ++i) dsum += va[i] * vb[i];
  }
  return dsum;
}

// shared prep body: LDS-broadcast GEMM (ends with __syncthreads; ls reusable)
__device__ __forceinline__ void prep_node(float f, int f32, int wid, int lane,
                                          const void* __restrict__ W,
                                          const void* __restrict__ att,
                                          unsigned char* __restrict__ fhat,
                                          __hip_bfloat16* __restrict__ Hmat,
                                          float* __restrict__ a_l,
                                          float* __restrict__ a_r,
                                          float* __restrict__ ls) {
  float n2 = wred_sum(f * f);
  float nrm = fmaxf(sqrtf(n2), EPS_COS);
  fhat[(size_t)wid * D + lane] = enc_fp8(f / nrm);
  ls[lane] = f;
  __syncthreads();
  float h0 = 0.f, h1 = 0.f, h2 = 0.f, h3 = 0.f;
  if (f32) {
    const float* Wf = (const float*)W;
#pragma unroll 4
    for (int k = 0; k < D; k += 4) {
      h0 += ls[k] * Wf[k * D + lane];
      h1 += ls[k + 1] * Wf[(k + 1) * D + lane];
      h2 += ls[k + 2] * Wf[(k + 2) * D + lane];
      h3 += ls[k + 3] * Wf[(k + 3) * D + lane];
    }
  } else {
    const __hip_bfloat16* Wb = (const __hip_bfloat16*)W;
#pragma unroll 4
    for (int k = 0; k < D; k += 4) {
      h0 += ls[k] * __bfloat162float(Wb[k * D + lane]);
      h1 += ls[k + 1] * __bfloat162float(Wb[(k + 1) * D + lane]);
      h2 += ls[k + 2] * __bfloat162float(Wb[(k + 2) * D + lane]);
      h3 += ls[k + 3] * __bfloat162float(Wb[(k + 3) * D + lane]);
    }
  }
  float Hc = (h0 + h1) + (h2 + h3);
  Hmat[(size_t)wid * D + lane] = __float2bfloat16(Hc);
  float al = wred_sum(Hc * ldv(att, lane, f32));
  float ar = wred_sum(Hc * ldv(att, D + lane, f32));
  if (lane == 0) {
    a_l[wid] = al;
    a_r[wid] = ar;
  }
  __syncthreads();
}

// ---------------- R22 fused front: direct scatter + prep0 + residual MLP ----------------
// grid=N, 64 threads. Block b: dtype detect + scatter its edge chunk + prep
// node b (W0) + residual MLP node b -> xres. Dense work rides in the scatter
// stall shadow (R18-measured effect).
__global__ void __launch_bounds__(64) k_all(const unsigned short* __restrict__ xu,
                                            const int* __restrict__ ei,
                                            const void* __restrict__ w,
                                            int* __restrict__ flags,
                                            int* __restrict__ cnt,
                                            const void* __restrict__ x,
                                            const void* __restrict__ W,
                                            const void* __restrict__ att,
                                            const void* __restrict__ rW1,
                                            const void* __restrict__ rb1,
                                            const void* __restrict__ rW2,
                                            const void* __restrict__ rb2,
                                            unsigned char* __restrict__ fhat,
                                            __hip_bfloat16* __restrict__ Hmat,
                                            float* __restrict__ a_l,
                                            float* __restrict__ a_r,
                                            float* __restrict__ xres,
                                            unsigned int* __restrict__ csr2,
                                            int N, int E) {
  __shared__ float ls[D];
  const int lane = threadIdx.x;
  const int b = blockIdx.x;
  // dtype detect: per-wave, register-only (x[0..63] / ei[0..127] are L2-hot)
  float dv = b2f(xu[lane]);
  float da = fabsf(dv);
  unsigned long long m = __ballot(da > 1e-4f && da < 100.f);
  unsigned long long m2 = __ballot(ei[2 * lane + 1] != 0);
  const int f32 = (__popcll(m) >= 60) ? 0 : 1;
  const int wide = (m2 == 0ull) ? 1 : 0;
  if (b == 0 && lane == 0) {
    flags[0] = f32;
    flags[1] = wide;
  }
  // ---- direct-scatter binning of this block's edge chunk ----
  const long long e0 = ((long long)b * E) / N;
  const long long e1 = ((long long)(b + 1) * E) / N;
  for (long long e = e0 + lane; e < e1; e += 64) {
    int ss, dd;
    if (wide) {
      ss = ei[2 * e];
      dd = ei[2 * (size_t)E + 2 * e];
    } else {
      ss = ei[e];
      dd = ei[(size_t)E + e];
    }
    float we = ldv(w, (size_t)e, f32);
    const int dc = min(max(dd, 0), N - 1);
    const int slot = atomicAdd(&cnt[dc], 1);
    if (slot < CAP)
      csr2[(size_t)dc * CAP + slot] = pack_sg(min(max(ss, 0), N - 1), gate_of(we));
  }
  if (b >= N) return;
  // ---- node prep (layer 0) ----
  float f = ldv(x, (size_t)b * D + lane, f32);
  prep_node(f, f32, b, lane, W, att, fhat, Hmat, a_l, a_r, ls);
  // ---- residual MLP: xres = relu(x@rW1+rb1)@rW2+rb2 (reuses f = x[b]) ----
  ls[lane] = f;
  __syncthreads();
  float h0 = ldv(rb1, lane, f32), h1 = 0.f, h2 = 0.f, h3 = 0.f;
  if (f32) {
    const float* w1 = (const float*)rW1;
#pragma unroll 4
    for (int k = 0; k < D; k += 4) {
      h0 += ls[k] * w1[k * D + lane];
      h1 += ls[k + 1] * w1[(k + 1) * D + lane];
      h2 += ls[k + 2] * w1[(k + 2) * D + lane];
      h3 += ls[k + 3] * w1[(k + 3) * D + lane];
    }
  } else {
    const __hip_bfloat16* w1 = (const __hip_bfloat16*)rW1;
#pragma unroll 4
    for (int k = 0; k < D; k += 4) {
      h0 += ls[k] * __bfloat162float(w1[k * D + lane]);
      h1 += ls[k + 1] * __bfloat162float(w1[(k + 1) * D + lane]);
      h2 += ls[k + 2] * __bfloat162float(w1[(k + 2) * D + lane]);
      h3 += ls[k + 3] * __bfloat162float(w1[(k + 3) * D + lane]);
    }
  }
  float tr = fmaxf((h0 + h1) + (h2 + h3), 0.f);
  __syncthreads();
  ls[lane] = tr;
  __syncthreads();
  float g0 = ldv(rb2, lane, f32), g1 = 0.f, g2 = 0.f, g3 = 0.f;
  if (f32) {
    const float* w2 = (const float*)rW2;
#pragma unroll 4
    for (int k = 0; k < D; k += 4) {
      g0 += ls[k] * w2[k * D + lane];
      g1 += ls[k + 1] * w2[(k + 1) * D + lane];
      g2 += ls[k + 2] * w2[(k + 2) * D + lane];
      g3 += ls[k + 3] * w2[(k + 3) * D + lane];
    }
  } else {
    const __hip_bfloat16* w2 = (const __hip_bfloat16*)rW2;
#pragma unroll 4
    for (int k = 0; k < D; k += 4) {
      g0 += ls[k] * __bfloat162float(w2[k * D + lane]);
      g1 += ls[k + 1] * __bfloat162float(w2[(k + 1) * D + lane]);
      g2 += ls[k + 2] * __bfloat162float(w2[(k + 2) * D + lane]);
      g3 += ls[k + 3] * __bfloat162float(w2[(k + 3) * D + lane]);
    }
  }
  xres[(size_t)b * D + lane] = (g0 + g1) + (g2 + g3);
}

// ---------------- legacy binning kernel (fallback tiers) ----------------
__global__ void __launch_bounds__(256) k_bin(const unsigned short* __restrict__ xu,
                                             const int* __restrict__ ei,
                                             const void* __restrict__ w,
                                             int* __restrict__ flags,
                                             int* __restrict__ cnt,
                                             unsigned int* __restrict__ csr2,
                                             int N, int E) {
  __shared__ int sf[2];
  const int tid = threadIdx.x;
  if (tid < 64) {
    float v = b2f(xu[tid]);
    float a = fabsf(v);
    unsigned long long m = __ballot(a > 1e-4f && a < 100.f);
    unsigned long long m2 = __ballot(ei[2 * tid + 1] != 0);
    if (tid == 0) {
      sf[0] = (__popcll(m) >= 60) ? 0 : 1;
      sf[1] = (m2 == 0ull) ? 1 : 0;
      if (blockIdx.x == 0) {
        flags[0] = sf[0];
        flags[1] = sf[1];
      }
    }
  }
  __syncthreads();
  const int f32 = sf[0], wide = sf[1];
  const int e0 = (blockIdx.x * 256 + tid) * 2;
  if (e0 >= E) return;
  const bool has1 = (e0 + 1 < E);
  int s0, s1, d0, d1;
  if (wide) {
    int4 vs = *(const int4*)(ei + 2 * (size_t)e0);
    int4 vd = *(const int4*)(ei + 2 * (size_t)E + 2 * (size_t)e0);
    s0 = vs.x; s1 = vs.z; d0 = vd.x; d1 = vd.z;
  } else {
    int2 vs = *(const int2*)(ei + e0);
    int2 vd = *(const int2*)(ei + (size_t)E + e0);
    s0 = vs.x; s1 = vs.y; d0 = vd.x; d1 = vd.y;
  }
  float w0, w1 = 0.f;
  if (f32) {
    float2 wv = *(const float2*)((const float*)w + e0);
    w0 = wv.x; w1 = wv.y;
  } else {
    const __hip_bfloat16* wb = (const __hip_bfloat16*)w;
    w0 = __bfloat162float(wb[e0]);
    if (has1) w1 = __bfloat162float(wb[e0 + 1]);
  }
  int d0c = min(max(d0, 0), N - 1);
  int slot0 = atomicAdd(&cnt[d0c], 1);
  if (slot0 < CAP)
    csr2[(size_t)d0c * CAP + slot0] = pack_sg(min(max(s0, 0), N - 1), gate_of(w0));
  if (has1) {
    int d1c = min(max(d1, 0), N - 1);
    int slot1 = atomicAdd(&cnt[d1c], 1);
    if (slot1 < CAP)
      csr2[(size_t)d1c * CAP + slot1] = pack_sg(min(max(s1, 0), N - 1), gate_of(w1));
  }
}

// ---------------- weight-resident node prep (grid-stride) ----------------
// xbf16: force-interpret xin as bf16 (internal hbuf), else use flags[0].
__global__ void __launch_bounds__(64, 4) k_prepW(const void* __restrict__ xin,
                                                 const void* __restrict__ W,
                                                 const void* __restrict__ att,
                                                 const int* __restrict__ flags,
                                                 unsigned char* __restrict__ fhat,
                                                 __hip_bfloat16* __restrict__ Hmat,
                                                 float* __restrict__ a_l,
                                                 float* __restrict__ a_r, int N,
                                                 int xbf16) {
  __shared__ float ls[D];
  const int lane = threadIdx.x;
  const int f32 = flags[0];
  const int xf32 = xbf16 ? 0 : f32;
  float wreg[D];
  if (f32) {
    const float* Wf = (const float*)W;
#pragma unroll
    for (int k = 0; k < D; ++k) wreg[k] = Wf[k * D + lane];
  } else {
    const __hip_bfloat16* Wb = (const __hip_bfloat16*)W;
#pragma unroll
    for (int k = 0; k < D; ++k) wreg[k] = __bfloat162float(Wb[k * D + lane]);
  }
  const float attl = ldv(att, lane, f32);
  const float attr = ldv(att, D + lane, f32);
  float f = (blockIdx.x < (unsigned)N) ? ldv(xin, (size_t)blockIdx.x * D + lane, xf32) : 0.f;
  for (int wid = blockIdx.x; wid < N; wid += gridDim.x) {
    const int nwid = wid + gridDim.x;
    float fnx = (nwid < N) ? ldv(xin, (size_t)nwid * D + lane, xf32) : 0.f;  // prefetch
    float n2 = wred_sum(f * f);
    float nrm = fmaxf(sqrtf(n2), EPS_COS);
    fhat[(size_t)wid * D + lane] = enc_fp8(f / nrm);
    ls[lane] = f;
    __syncthreads();
    float h0 = 0.f, h1 = 0.f, h2 = 0.f, h3 = 0.f;
#pragma unroll
    for (int k = 0; k < D; k += 4) {
      h0 += ls[k] * wreg[k];
      h1 += ls[k + 1] * wreg[k + 1];
      h2 += ls[k + 2] * wreg[k + 2];
      h3 += ls[k + 3] * wreg[k + 3];
    }
    float Hc = (h0 + h1) + (h2 + h3);
    Hmat[(size_t)wid * D + lane] = __float2bfloat16(Hc);
    float al = wred_sum(Hc * attl);
    float ar = wred_sum(Hc * attr);
    if (lane == 0) {
      a_l[wid] = al;
      a_r[wid] = ar;
    }
    __syncthreads();
    f = fnx;
  }
}

// standalone prep (legacy non-fused tier) — 64-thread, grid=N
__global__ void __launch_bounds__(64) k_prep(const void* __restrict__ xin,
                                             const void* __restrict__ W,
                                             const void* __restrict__ att,
                                             const int* __restrict__ flags,
                                             unsigned char* __restrict__ fhat,
                                             __hip_bfloat16* __restrict__ Hmat,
                                             float* __restrict__ a_l,
                                             float* __restrict__ a_r, int N) {
  __shared__ float ls[D];
  const int lane = threadIdx.x;
  const int wid = blockIdx.x;
  if (wid >= N) return;
  const int f32 = flags[0];
  float f = ldv(xin, (size_t)wid * D + lane, f32);
  prep_node(f, f32, wid, lane, W, att, fhat, Hmat, a_l, a_r, ls);
}

// ---------------- edge kernel: ONE wave per dst node (64-thread blocks) ----------------
// modes: 0=prep epilogue (legacy), 1=in-kernel MLP (legacy), 2=store native,
//        3=v + xres -> out (main), 4=store bf16 (hbuf, main)
__global__ void __launch_bounds__(64, 8) k_edge(const int* __restrict__ cnt,
                                                const unsigned int* __restrict__ csr2,
                                                const int* __restrict__ ei,
                                                const void* __restrict__ w,
                                                const unsigned char* __restrict__ fhat,
                                                const __hip_bfloat16* __restrict__ Hmat,
                                                const float* __restrict__ a_l,
                                                const float* __restrict__ a_r,
                                                const void* __restrict__ beta,
                                                const void* __restrict__ bias,
                                                const void* __restrict__ x,
                                                const void* __restrict__ rW1,
                                                const void* __restrict__ rb1,
                                                const void* __restrict__ rW2,
                                                const void* __restrict__ rb2,
                                                const void* __restrict__ Wn,
                                                const void* __restrict__ attn,
                                                unsigned char* __restrict__ fh2,
                                                __hip_bfloat16* __restrict__ Hm2,
                                                float* __restrict__ al2,
                                                float* __restrict__ ar2,
                                                const float* __restrict__ xres,
                                                const int* __restrict__ flags,
                                                void* __restrict__ out,
                                                int N, int E, int mode) {
  const int lane = threadIdx.x;
  const int wid = blockIdx.x;
  __shared__ float2 lc[CAP];  // (l, c) per edge
  __shared__ float2 sg[CAP];  // (src bits, p) — written in phase 2
  __shared__ float lds_t[D];  // acc transpose; reused as GEMM staging in epilogue
  if (wid >= N) return;
  const int f32 = flags[0];
  const int g = lane >> 3;   // edge slot in 8-edge group
  const int sub = lane & 7;  // feature block: [8*sub, 8*sub+8)
  const int degRaw = cnt[wid];
  const float aln = a_l[wid];
  const float bb = 1.f / (1.f + __expf(-ldv(beta, 0, f32)));
  const float ob = 1.f - bb;
  const char* HmatB = (const char*)Hmat;

  float v;  // pre-elu output feature for this lane
  if (degRaw <= CAP) {
    // ================= fast path (always taken on bench data) =================
    const int deg = degRaw;
    const int s = wid * CAP;
    float fn[8];
    dec_fp8x8(*(const uint2*)(fhat + (((unsigned)wid << 6) | ((unsigned)sub << 3))), fn);

    // ---- phase 1 (iters 0-3, static): fp8 gathers + Hmat prefetch to regs ----
    float m1 = -1e30f, m2 = -1e30f;
    uint4 hm[4];
#pragma unroll
    for (int kk = 0; kk < 4; ++kk) {
      const int base = kk * 8;
      if (base < deg) {
        const int j = base + g;
        const bool val = j < deg;
        const unsigned int en = val ? csr2[s + j] : (unsigned int)wid;
        const unsigned src = (unsigned)upk_src(en, N);
        float hv[8];
        dec_fp8x8(*(const uint2*)(fhat + ((src << 6) | ((unsigned)sub << 3))), hv);
        hm[kk] = *(const uint4*)(HmatB + ((src << 7) | ((unsigned)sub << 4)));
        float d = 0.f;
#pragma unroll
        for (int i = 0; i < 8; ++i) d += fn[i] * hv[i];
        d += __shfl_xor(d, 1, 64);
        d += __shfl_xor(d, 2, 64);
        d += __shfl_xor(d, 4, 64);
        float l = aln + a_r[src];
        l = (l >= 0.f) ? l : NEG_SLOPE * l;
        if (val) {
          m1 = fmaxf(m1, l);
          m2 = fmaxf(m2, d);
          if (sub == 0) lc[j] = make_float2(l, d);
        }
      }
    }
    // tail iterations (deg > 32): no prefetch
    for (int base = 32; base < deg; base += 8) {
      const int j = base + g;
      const bool val = j < deg;
      const unsigned int en = val ? csr2[s + j] : (unsigned int)wid;
      const unsigned src = (unsigned)upk_src(en, N);
      float hv[8];
      dec_fp8x8(*(const uint2*)(fhat + ((src << 6) | ((unsigned)sub << 3))), hv);
      float d = 0.f;
#pragma unroll
      for (int i = 0; i < 8; ++i) d += fn[i] * hv[i];
      d += __shfl_xor(d, 1, 64);
      d += __shfl_xor(d, 2, 64);
      d += __shfl_xor(d, 4, 64);
      float l = aln + a_r[src];
      l = (l >= 0.f) ? l : NEG_SLOPE * l;
      if (val) {
        m1 = fmaxf(m1, l);
        m2 = fmaxf(m2, d);
        if (sub == 0) lc[j] = make_float2(l, d);
      }
    }
    m1 = fmaxf(m1, __shfl_xor(m1, 8, 64));
    m1 = fmaxf(m1, __shfl_xor(m1, 16, 64));
    m1 = fmaxf(m1, __shfl_xor(m1, 32, 64));
    m2 = fmaxf(m2, __shfl_xor(m2, 8, 64));
    m2 = fmaxf(m2, __shfl_xor(m2, 16, 64));
    m2 = fmaxf(m2, __shfl_xor(m2, 32, 64));

    // ---- phase 2: dual softmax sums + fused p (deg <= 64 always) ----
    float el0 = 0.f, ec0 = 0.f, gg0 = 0.f;
    int q0 = 0;
    float ps1 = 0.f, ps2 = 0.f;
    if (lane < deg) {
      const unsigned int en = csr2[s + lane];  // coalesced, L2-hot
      q0 = upk_src(en, N);
      gg0 = upk_gate(en);
      float2 t = lc[lane];
      el0 = __expf(t.x - m1);
      ec0 = __expf(t.y - m2);
      ps1 = el0;
      ps2 = ec0;
    }
    const float rs1 = 1.f / (wred_sum(ps1) + EPS_SM);
    const float rs2 = 1.f / (wred_sum(ps2) + EPS_SM);

    float sp = 0.f;
    if (lane < deg) {
      float tt = (ob * el0 * rs1 + bb * ec0 * rs2) * gg0;
      float p0 = __expf(tt - 1.f);
      sp = p0;
      sg[lane] = make_float2(__int_as_float(q0), p0);  // (src, p)
    }
    const float rinv = 1.f / (wred_sum(sp) + EPS_SM);

    // ---- phase 3: register-resident Hmat for iters 0-3; gathers for tail ----
    float acc[8] = {0.f, 0.f, 0.f, 0.f, 0.f, 0.f, 0.f, 0.f};
#pragma unroll
    for (int kk = 0; kk < 4; ++kk) {
      const int base = kk * 8;
      if (base < deg) {
        const int j = base + g;
        const float pv = (j < deg) ? sg[j].y : 0.f;
        float hv[8];
        unp8(hm[kk], hv);
#pragma unroll
        for (int i = 0; i < 8; ++i) acc[i] += pv * hv[i];
      }
    }
    for (int base = 32; base < deg; base += 8) {
      const int j = base + g;
      float2 en = (j < deg) ? sg[j] : make_float2(__int_as_float(wid), 0.f);
      const float pv = en.y;
      const unsigned srcv = (unsigned)__float_as_int(en.x);
      float hv[8];
      unp8(*(const uint4*)(HmatB + ((srcv << 7) | ((unsigned)sub << 4))), hv);
#pragma unroll
      for (int i = 0; i < 8; ++i) acc[i] += pv * hv[i];
    }
#pragma unroll
    for (int i = 0; i < 8; ++i) {
      acc[i] += __shfl_xor(acc[i], 8, 64);
      acc[i] += __shfl_xor(acc[i], 16, 64);
      acc[i] += __shfl_xor(acc[i], 32, 64);
    }
    if (g == 0) {
#pragma unroll
      for (int i = 0; i < 8; ++i) lds_t[8 * sub + i] = acc[i];
    }
    v = lds_t[lane] * rinv + ldv(bias, lane, f32);
  } else {
    // ============ slow path: exact 3-pass over raw edge list ============
    const int wide = flags[1];
    lds_t[lane] = 0.f;
    float m1 = -1e30f, m2 = -1e30f;
    for (int e64 = lane; e64 < E; e64 += 64) {
      int dd = wide ? ei[2 * (size_t)E + 2 * (size_t)e64] : ei[(size_t)E + e64];
      if (dd != wid) continue;
      int ss = wide ? ei[2 * (size_t)e64] : ei[e64];
      ss = min(max(ss, 0), N - 1);
      float l = aln + a_r[ss];
      l = (l >= 0.f) ? l : NEG_SLOPE * l;
      float c = slow_cos(fhat, wid, ss);
      m1 = fmaxf(m1, l);
      m2 = fmaxf(m2, c);
    }
    m1 = wred_max(m1);
    m2 = wred_max(m2);
    float ps1 = 0.f, ps2 = 0.f;
    for (int e64 = lane; e64 < E; e64 += 64) {
      int dd = wide ? ei[2 * (size_t)E + 2 * (size_t)e64] : ei[(size_t)E + e64];
      if (dd != wid) continue;
      int ss = wide ? ei[2 * (size_t)e64] : ei[e64];
      ss = min(max(ss, 0), N - 1);
      float l = aln + a_r[ss];
      l = (l >= 0.f) ? l : NEG_SLOPE * l;
      float c = slow_cos(fhat, wid, ss);
      ps1 += __expf(l - m1);
      ps2 += __expf(c - m2);
    }
    const float rs1 = 1.f / (wred_sum(ps1) + EPS_SM);
    const float rs2 = 1.f / (wred_sum(ps2) + EPS_SM);
    float sp = 0.f;
    for (int e64 = lane; e64 < E; e64 += 64) {
      int dd = wide ? ei[2 * (size_t)E + 2 * (size_t)e64] : ei[(size_t)E + e64];
      if (dd != wid) continue;
      int ss = wide ? ei[2 * (size_t)e64] : ei[e64];
      ss = min(max(ss, 0), N - 1);
      float l = aln + a_r[ss];
      l = (l >= 0.f) ? l : NEG_SLOPE * l;
      float c = slow_cos(fhat, wid, ss);
      float gx = gate_of(ldv(w, e64, f32));
      float px = __expf((ob * __expf(l - m1) * rs1 + bb * __expf(c - m2) * rs2) * gx - 1.f);
      sp += px;
      for (int q = 0; q < D; ++q)
        atomicAdd(&lds_t[q], px * __bfloat162float(Hmat[(size_t)ss * D + q]));
    }
    const float rinv = 1.f / (wred_sum(sp) + EPS_SM);
    v = lds_t[lane] * rinv + ldv(bias, lane, f32);
  }

  v = elu1(v);  // elu inside _cosgat
  if (mode == 3) {
    float a2 = xres[(size_t)wid * D + lane];
    stv(out, (size_t)wid * D + lane, f32, sane(v + a2));
  } else if (mode == 1) {
    // legacy: fused residual MLP — LDS-broadcast GEMMs
    float xv = ldv(x, (size_t)wid * D + lane, f32);
    float b0_ = ldv(rb1, lane, f32);
    __syncthreads();
    lds_t[lane] = xv;
    __syncthreads();
    float a2;
    float h0 = 0.f, h1 = 0.f, h2 = 0.f, h3 = 0.f;
    if (f32) {
      const float* w1 = (const float*)rW1;
      const float* w2 = (const float*)rW2;
#pragma unroll 4
      for (int k = 0; k < D; k += 4) {
        h0 += lds_t[k] * w1[k * D + lane];
        h1 += lds_t[k + 1] * w1[(k + 1) * D + lane];
        h2 += lds_t[k + 2] * w1[(k + 2) * D + lane];
        h3 += lds_t[k + 3] * w1[(k + 3) * D + lane];
      }
      float tr = fmaxf(b0_ + (h0 + h1) + (h2 + h3), 0.f);
      __syncthreads();
      lds_t[lane] = tr;
      __syncthreads();
      float g0 = 0.f, g1 = 0.f, g2 = 0.f, g3 = 0.f;
#pragma unroll 4
      for (int k = 0; k < D; k += 4) {
        g0 += lds_t[k] * w2[k * D + lane];
        g1 += lds_t[k + 1] * w2[(k + 1) * D + lane];
        g2 += lds_t[k + 2] * w2[(k + 2) * D + lane];
        g3 += lds_t[k + 3] * w2[(k + 3) * D + lane];
      }
      a2 = ((const float*)rb2)[lane] + (g0 + g1) + (g2 + g3);
    } else {
      const __hip_bfloat16* w1 = (const __hip_bfloat16*)rW1;
      const __hip_bfloat16* w2 = (const __hip_bfloat16*)rW2;
#pragma unroll 4
      for (int k = 0; k < D; k += 4) {
        h0 += lds_t[k] * __bfloat162float(w1[k * D + lane]);
        h1 += lds_t[k + 1] * __bfloat162float(w1[(k + 1) * D + lane]);
        h2 += lds_t[k + 2] * __bfloat162float(w1[(k + 2) * D + lane]);
        h3 += lds_t[k + 3] * __bfloat162float(w1[(k + 3) * D + lane]);
      }
      float tr = fmaxf(b0_ + (h0 + h1) + (h2 + h3), 0.f);
      __syncthreads();
      lds_t[lane] = tr;
      __syncthreads();
      float g0 = 0.f, g1 = 0.f, g2 = 0.f, g3 = 0.f;
#pragma unroll 4
      for (int k = 0; k < D; k += 4) {
        g0 += lds_t[k] * __bfloat162float(w2[k * D + lane]);
        g1 += lds_t[k + 1] * __bfloat162float(w2[(k + 1) * D + lane]);
        g2 += lds_t[k + 2] * __bfloat162float(w2[(k + 2) * D + lane]);
        g3 += lds_t[k + 3] * __bfloat162float(w2[(k + 3) * D + lane]);
      }
      a2 = __bfloat162float(((const __hip_bfloat16*)rb2)[lane]) + (g0 + g1) + (g2 + g3);
    }
    stv(out, (size_t)wid * D + lane, f32, sane(v + a2));
  } else {
    v = elu1(v);  // inter-layer elu
    if (mode == 0) {
      __syncthreads();
      prep_node(sane(v), f32, wid, lane, Wn, attn, fh2, Hm2, al2, ar2, lds_t);
    } else if (mode == 4) {  // store bf16 (internal hbuf)
      stv(out, (size_t)wid * D + lane, 0, sane(v));
    } else {  // mode 2: store native dtype
      stv(out, (size_t)wid * D + lane, f32, sane(v));
    }
  }
}

extern "C" void kernel_launch(void* const* d_in, const int* in_sizes, int n_in,
                              void* d_out, int out_size, void* d_ws, size_t ws_size,
                              hipStream_t stream) {
  const void* x = d_in[0];
  const int* ei = (const int*)d_in[1];
  const void* w = d_in[2];
  const void* W0 = d_in[3];
  const void* att0 = d_in[4];
  const void* beta0 = d_in[5];
  const void* b0 = d_in[6];
  const void* W1 = d_in[7];
  const void* att1 = d_in[8];
  const void* beta1 = d_in[9];
  const void* b1 = d_in[10];
  const void* rW1 = d_in[11];
  const void* rb1 = d_in[12];
  const void* rW2 = d_in[13];
  const void* rb2 = d_in[14];

  const int N = in_sizes[0] / D;
  const int E = in_sizes[2];

  char* base = (char*)d_ws;
  size_t off = 0;
  auto alloc = [&](size_t bytes) -> void* {
    void* p = base + off;
    off += (bytes + 255) & ~(size_t)255;
    return p;
  };
  // common tier
  int* flags = (int*)alloc(256);
  int* cnt = (int*)alloc((size_t)N * 4);
  unsigned int* csr2 = (unsigned int*)alloc((size_t)N * CAP * 4);
  unsigned char* fhat = (unsigned char*)alloc((size_t)N * D);
  __hip_bfloat16* Hmat = (__hip_bfloat16*)alloc((size_t)N * D * 2);
  float* a_l = (float*)alloc((size_t)N * 4);
  float* a_r = (float*)alloc((size_t)N * 4);
  const size_t common_off = off;
  // tier A (main): hbuf (bf16) + xres (f32)
  __hip_bfloat16* hbuf = (__hip_bfloat16*)alloc((size_t)N * D * 2);
  float* xres = (float*)alloc((size_t)N * D * 4);
  const bool tierA = (off <= ws_size);
  // tier B (legacy fused): second-layer prep buffers (alias tier-A region)
  off = common_off;
  unsigned char* fhat2 = (unsigned char*)alloc((size_t)N * D);
  __hip_bfloat16* Hmat2 = (__hip_bfloat16*)alloc((size_t)N * D * 2);
  float* a_l2 = (float*)alloc((size_t)N * 4);
  float* a_r2 = (float*)alloc((size_t)N * 4);
  const bool tierB = (off <= ws_size);

  const int eb2 = (E / 2 + 255) / 256;

  hipMemsetAsync(cnt, 0, (size_t)N * 4, stream);

  if (tierA) {
    // 5 dispatches: k_all (scatter+prep0+MLP) -> edge(4) -> prepW(hbuf) -> edge(3)
    k_all<<<N, 64, 0, stream>>>((const unsigned short*)x, ei, w, flags, cnt,
                                x, W0, att0, rW1, rb1, rW2, rb2,
                                fhat, Hmat, a_l, a_r, xres, csr2, N, E);
    k_edge<<<N, 64, 0, stream>>>(cnt, csr2, ei, w, fhat, Hmat, a_l, a_r,
                                 beta0, b0, x, rW1, rb1, rW2, rb2,
                                 nullptr, nullptr, nullptr, nullptr, nullptr, nullptr,
                                 nullptr, flags, hbuf, N, E, 4);
    k_prepW<<<4096, 64, 0, stream>>>(hbuf, W1, att1, flags, fhat, Hmat, a_l, a_r,
                                     N, 1);
    k_edge<<<N, 64, 0, stream>>>(cnt, csr2, ei, w, fhat, Hmat, a_l, a_r,
                                 beta1, b1, x, rW1, rb1, rW2, rb2,
                                 nullptr, nullptr, nullptr, nullptr, nullptr, nullptr,
                                 xres, flags, d_out, N, E, 3);
  } else if (tierB) {
    k_bin<<<eb2, 256, 0, stream>>>((const unsigned short*)x, ei, w, flags, cnt,
                                   csr2, N, E);
    k_prep<<<N, 64, 0, stream>>>(x, W0, att0, flags, fhat, Hmat, a_l, a_r, N);
    k_edge<<<N, 64, 0, stream>>>(cnt, csr2, ei, w, fhat, Hmat, a_l, a_r,
                                 beta0, b0, x, rW1, rb1, rW2, rb2,
                                 W1, att1, fhat2, Hmat2, a_l2, a_r2,
                                 nullptr, flags, d_out, N, E, 0);
    k_edge<<<N, 64, 0, stream>>>(cnt, csr2, ei, w, fhat2, Hmat2, a_l2, a_r2,
                                 beta1, b1, x, rW1, rb1, rW2, rb2,
                                 nullptr, nullptr, nullptr, nullptr, nullptr, nullptr,
                                 nullptr, flags, d_out, N, E, 1);
  } else {
    k_bin<<<eb2, 256, 0, stream>>>((const unsigned short*)x, ei, w, flags, cnt,
                                   csr2, N, E);
    k_prep<<<N, 64, 0, stream>>>(x, W0, att0, flags, fhat, Hmat, a_l, a_r, N);
    k_edge<<<N, 64, 0, stream>>>(cnt, csr2, ei, w, fhat, Hmat, a_l, a_r,
                                 beta0, b0, x, rW1, rb1, rW2, rb2,
                                 nullptr, nullptr, nullptr, nullptr, nullptr, nullptr,
                                 nullptr, flags, d_out, N, E, 2);
    k_prep<<<N, 64, 0, stream>>>(d_out, W1, att1, flags, fhat, Hmat, a_l, a_r, N);
    k_edge<<<N, 64, 0, stream>>>(cnt, csr2, ei, w, fhat, Hmat, a_l, a_r,
                                 beta1, b1, x, rW1, rb1, rW2, rb2,
                                 nullptr, nullptr, nullptr, nullptr, nullptr, nullptr,
                                 nullptr, flags, d_out, N, E, 1);
  }
}

// Round 11
// 327.313 us; speedup vs baseline: 1.8459x; 1.0521x over previous
//
#include <hip/hip_runtime.h>
#include <hip/hip_bf16.h>
#include <math.h>

// COSGATEncoder: N=50000, E=1280000, D=64, HEADS=1. f32 in/out (runtime-detected,
// bf16 fallback), edge_index int64 (runtime-detected, int32 fallback).
// R23: recomposition of measured pieces. R22 ledger: k_all 130 + edge 62x2 +
// memset ~= 260, measured 344 -> separate k_prepW + gaps cost ~85us, while
// R18-measured mode-0 (prep fused in edge epilogue) costs only +36us and zero
// gaps. So tier A = memset, k_all (scatter + prep0 + resMLP->xres, unchanged),
// k_edge mode 0 (thin phases + LDS-broadcast layer-1 prep -> fhat2/Hmat2),
// k_edge mode 3 (thin + xres -> out). 4 dispatches, no k_prepW, no hbuf.
// Rest: 1-wave k_edge w/ reg-resident Hmat (deg<=32), slot-CSR direct scatter
// (5-experiment floor ~100-130us; dense work rides its stall shadow), exact
// slow path deg>CAP, fp8 fhat rows, packed 4B csr, LDS-broadcast GEMMs.

constexpr int D = 64;
constexpr int CAP = 64;
constexpr float NEG_SLOPE = 0.2f;
constexpr float EPS_COS = 1e-8f;
constexpr float EPS_SM = 1e-16f;

#if defined(__has_builtin)
#if __has_builtin(__builtin_amdgcn_cvt_pk_f32_fp8) && __has_builtin(__builtin_amdgcn_cvt_pk_fp8_f32)
#define HW_FP8 1
#endif
#endif

typedef float floatx2 __attribute__((ext_vector_type(2)));

__device__ __forceinline__ float wred_sum(float v) {
#pragma unroll
  for (int off = 32; off > 0; off >>= 1) v += __shfl_xor(v, off, 64);
  return v;
}
__device__ __forceinline__ float wred_max(float v) {
#pragma unroll
  for (int off = 32; off > 0; off >>= 1) v = fmaxf(v, __shfl_xor(v, off, 64));
  return v;
}
__device__ __forceinline__ float elu1(float x) { return x > 0.f ? x : __expf(x) - 1.f; }
__device__ __forceinline__ float sane(float v) {
  return (v == v && fabsf(v) < 1e30f) ? v : 0.f;
}
__device__ __forceinline__ float ldv(const void* p, size_t i, int f32) {
  return f32 ? ((const float*)p)[i]
             : __bfloat162float(((const __hip_bfloat16*)p)[i]);
}
__device__ __forceinline__ void stv(void* p, size_t i, int f32, float v) {
  if (f32) ((float*)p)[i] = v;
  else ((__hip_bfloat16*)p)[i] = __float2bfloat16(v);
}
__device__ __forceinline__ float b2f(unsigned short u) {
  return __uint_as_float(((unsigned int)u) << 16);
}
__device__ __forceinline__ void unp8(uint4 u, float* f) {
  f[0] = __uint_as_float(u.x << 16);
  f[1] = __uint_as_float(u.x & 0xffff0000u);
  f[2] = __uint_as_float(u.y << 16);
  f[3] = __uint_as_float(u.y & 0xffff0000u);
  f[4] = __uint_as_float(u.z << 16);
  f[5] = __uint_as_float(u.z & 0xffff0000u);
  f[6] = __uint_as_float(u.w << 16);
  f[7] = __uint_as_float(u.w & 0xffff0000u);
}

// ---- fp8 helpers: HW e4m3 when available, f16-msb (e5m2-like) fallback ----
__device__ __forceinline__ unsigned char enc_fp8(float v) {
#ifdef HW_FP8
  int pk = __builtin_amdgcn_cvt_pk_fp8_f32(v, v, 0, false);
  return (unsigned char)(pk & 0xFF);
#else
  _Float16 h = (_Float16)v;
  unsigned short ub;
  __builtin_memcpy(&ub, &h, 2);
  return (unsigned char)((ub + 0x80) >> 8);  // RNE-ish truncate to top byte
#endif
}
__device__ __forceinline__ void dec_fp8x8(uint2 u, float* f) {
#ifdef HW_FP8
  floatx2 a = __builtin_amdgcn_cvt_pk_f32_fp8(u.x, false);
  floatx2 b = __builtin_amdgcn_cvt_pk_f32_fp8(u.x, true);
  floatx2 c = __builtin_amdgcn_cvt_pk_f32_fp8(u.y, false);
  floatx2 d = __builtin_amdgcn_cvt_pk_f32_fp8(u.y, true);
  f[0] = a[0]; f[1] = a[1]; f[2] = b[0]; f[3] = b[1];
  f[4] = c[0]; f[5] = c[1]; f[6] = d[0]; f[7] = d[1];
#else
#pragma unroll
  for (int i = 0; i < 8; ++i) {
    unsigned int byte = (i < 4 ? (u.x >> (8 * i)) : (u.y >> (8 * (i - 4)))) & 0xFF;
    unsigned short hb = (unsigned short)(byte << 8);
    _Float16 h;
    __builtin_memcpy(&h, &hb, 2);
    f[i] = (float)h;
  }
#endif
}

// packed csr entry: bits 0..17 = src, bits 18..31 = gate quantized to 14 bits
__device__ __forceinline__ unsigned int pack_sg(int src, float g) {
  int gq = (int)(g * 16383.f + 0.5f);
  return ((unsigned int)src & 0x3FFFFu) | ((unsigned int)gq << 18);
}
__device__ __forceinline__ int upk_src(unsigned int e, int N) {
  return min((int)(e & 0x3FFFFu), N - 1);
}
__device__ __forceinline__ float upk_gate(unsigned int e) {
  return (float)(e >> 18) * (1.f / 16383.f);
}
__device__ __forceinline__ float gate_of(float w) {
  return fminf(fmaxf(1.f - 0.25f * fminf(w, 4.f), 0.f), 1.f);
}

// full fp8-row cosine dot (slow path only)
__device__ float slow_cos(const unsigned char* __restrict__ fhat, int a, int b) {
  const uint2* fa = (const uint2*)(fhat + (size_t)a * D);
  const uint2* fb = (const uint2*)(fhat + (size_t)b * D);
  float dsum = 0.f;
  for (int q = 0; q < 8; ++q) {
    float va[8], vb[8];
    dec_fp8x8(fa[q], va);
    dec_fp8x8(fb[q], vb);
#pragma unroll
    for (int i = 0; i < 8; ++i) dsum += va[i] * vb[i];
  }
  return dsum;
}

// shared prep body: LDS-broadcast GEMM (ends with __syncthreads; ls reusable)
__device__ __forceinline__ void prep_node(float f, int f32, int wid, int lane,
                                          const void* __restrict__ W,
                                          const void* __restrict__ att,
                                          unsigned char* __restrict__ fhat,
                                          __hip_bfloat16* __restrict__ Hmat,
                                          float* __restrict__ a_l,
                                          float* __restrict__ a_r,
                                          float* __restrict__ ls) {
  float n2 = wred_sum(f * f);
  float nrm = fmaxf(sqrtf(n2), EPS_COS);
  fhat[(size_t)wid * D + lane] = enc_fp8(f / nrm);
  ls[lane] = f;
  __syncthreads();
  float h0 = 0.f, h1 = 0.f, h2 = 0.f, h3 = 0.f;
  if (f32) {
    const float* Wf = (const float*)W;
#pragma unroll 4
    for (int k = 0; k < D; k += 4) {
      h0 += ls[k] * Wf[k * D + lane];
      h1 += ls[k + 1] * Wf[(k + 1) * D + lane];
      h2 += ls[k + 2] * Wf[(k + 2) * D + lane];
      h3 += ls[k + 3] * Wf[(k + 3) * D + lane];
    }
  } else {
    const __hip_bfloat16* Wb = (const __hip_bfloat16*)W;
#pragma unroll 4
    for (int k = 0; k < D; k += 4) {
      h0 += ls[k] * __bfloat162float(Wb[k * D + lane]);
      h1 += ls[k + 1] * __bfloat162float(Wb[(k + 1) * D + lane]);
      h2 += ls[k + 2] * __bfloat162float(Wb[(k + 2) * D + lane]);
      h3 += ls[k + 3] * __bfloat162float(Wb[(k + 3) * D + lane]);
    }
  }
  float Hc = (h0 + h1) + (h2 + h3);
  Hmat[(size_t)wid * D + lane] = __float2bfloat16(Hc);
  float al = wred_sum(Hc * ldv(att, lane, f32));
  float ar = wred_sum(Hc * ldv(att, D + lane, f32));
  if (lane == 0) {
    a_l[wid] = al;
    a_r[wid] = ar;
  }
  __syncthreads();
}

// ---------------- fused front: direct scatter + prep0 + residual MLP ----------------
// grid=N, 64 threads. Block b: dtype detect + scatter its edge chunk + prep
// node b (W0) + residual MLP node b -> xres. Dense work rides in the scatter
// stall shadow (R18/R22-measured effect).
__global__ void __launch_bounds__(64) k_all(const unsigned short* __restrict__ xu,
                                            const int* __restrict__ ei,
                                            const void* __restrict__ w,
                                            int* __restrict__ flags,
                                            int* __restrict__ cnt,
                                            const void* __restrict__ x,
                                            const void* __restrict__ W,
                                            const void* __restrict__ att,
                                            const void* __restrict__ rW1,
                                            const void* __restrict__ rb1,
                                            const void* __restrict__ rW2,
                                            const void* __restrict__ rb2,
                                            unsigned char* __restrict__ fhat,
                                            __hip_bfloat16* __restrict__ Hmat,
                                            float* __restrict__ a_l,
                                            float* __restrict__ a_r,
                                            float* __restrict__ xres,
                                            unsigned int* __restrict__ csr2,
                                            int N, int E) {
  __shared__ float ls[D];
  const int lane = threadIdx.x;
  const int b = blockIdx.x;
  // dtype detect: per-wave, register-only (x[0..63] / ei[0..127] are L2-hot)
  float dv = b2f(xu[lane]);
  float da = fabsf(dv);
  unsigned long long m = __ballot(da > 1e-4f && da < 100.f);
  unsigned long long m2 = __ballot(ei[2 * lane + 1] != 0);
  const int f32 = (__popcll(m) >= 60) ? 0 : 1;
  const int wide = (m2 == 0ull) ? 1 : 0;
  if (b == 0 && lane == 0) {
    flags[0] = f32;
    flags[1] = wide;
  }
  // ---- direct-scatter binning of this block's edge chunk ----
  const long long e0 = ((long long)b * E) / N;
  const long long e1 = ((long long)(b + 1) * E) / N;
  for (long long e = e0 + lane; e < e1; e += 64) {
    int ss, dd;
    if (wide) {
      ss = ei[2 * e];
      dd = ei[2 * (size_t)E + 2 * e];
    } else {
      ss = ei[e];
      dd = ei[(size_t)E + e];
    }
    float we = ldv(w, (size_t)e, f32);
    const int dc = min(max(dd, 0), N - 1);
    const int slot = atomicAdd(&cnt[dc], 1);
    if (slot < CAP)
      csr2[(size_t)dc * CAP + slot] = pack_sg(min(max(ss, 0), N - 1), gate_of(we));
  }
  if (b >= N) return;
  // ---- node prep (layer 0) ----
  float f = ldv(x, (size_t)b * D + lane, f32);
  prep_node(f, f32, b, lane, W, att, fhat, Hmat, a_l, a_r, ls);
  // ---- residual MLP: xres = relu(x@rW1+rb1)@rW2+rb2 (reuses f = x[b]) ----
  ls[lane] = f;
  __syncthreads();
  float h0 = ldv(rb1, lane, f32), h1 = 0.f, h2 = 0.f, h3 = 0.f;
  if (f32) {
    const float* w1 = (const float*)rW1;
#pragma unroll 4
    for (int k = 0; k < D; k += 4) {
      h0 += ls[k] * w1[k * D + lane];
      h1 += ls[k + 1] * w1[(k + 1) * D + lane];
      h2 += ls[k + 2] * w1[(k + 2) * D + lane];
      h3 += ls[k + 3] * w1[(k + 3) * D + lane];
    }
  } else {
    const __hip_bfloat16* w1 = (const __hip_bfloat16*)rW1;
#pragma unroll 4
    for (int k = 0; k < D; k += 4) {
      h0 += ls[k] * __bfloat162float(w1[k * D + lane]);
      h1 += ls[k + 1] * __bfloat162float(w1[(k + 1) * D + lane]);
      h2 += ls[k + 2] * __bfloat162float(w1[(k + 2) * D + lane]);
      h3 += ls[k + 3] * __bfloat162float(w1[(k + 3) * D + lane]);
    }
  }
  float tr = fmaxf((h0 + h1) + (h2 + h3), 0.f);
  __syncthreads();
  ls[lane] = tr;
  __syncthreads();
  float g0 = ldv(rb2, lane, f32), g1 = 0.f, g2 = 0.f, g3 = 0.f;
  if (f32) {
    const float* w2 = (const float*)rW2;
#pragma unroll 4
    for (int k = 0; k < D; k += 4) {
      g0 += ls[k] * w2[k * D + lane];
      g1 += ls[k + 1] * w2[(k + 1) * D + lane];
      g2 += ls[k + 2] * w2[(k + 2) * D + lane];
      g3 += ls[k + 3] * w2[(k + 3) * D + lane];
    }
  } else {
    const __hip_bfloat16* w2 = (const __hip_bfloat16*)rW2;
#pragma unroll 4
    for (int k = 0; k < D; k += 4) {
      g0 += ls[k] * __bfloat162float(w2[k * D + lane]);
      g1 += ls[k + 1] * __bfloat162float(w2[(k + 1) * D + lane]);
      g2 += ls[k + 2] * __bfloat162float(w2[(k + 2) * D + lane]);
      g3 += ls[k + 3] * __bfloat162float(w2[(k + 3) * D + lane]);
    }
  }
  xres[(size_t)b * D + lane] = (g0 + g1) + (g2 + g3);
}

// ---------------- legacy binning kernel (fallback tiers) ----------------
__global__ void __launch_bounds__(256) k_bin(const unsigned short* __restrict__ xu,
                                             const int* __restrict__ ei,
                                             const void* __restrict__ w,
                                             int* __restrict__ flags,
                                             int* __restrict__ cnt,
                                             unsigned int* __restrict__ csr2,
                                             int N, int E) {
  __shared__ int sf[2];
  const int tid = threadIdx.x;
  if (tid < 64) {
    float v = b2f(xu[tid]);
    float a = fabsf(v);
    unsigned long long m = __ballot(a > 1e-4f && a < 100.f);
    unsigned long long m2 = __ballot(ei[2 * tid + 1] != 0);
    if (tid == 0) {
      sf[0] = (__popcll(m) >= 60) ? 0 : 1;
      sf[1] = (m2 == 0ull) ? 1 : 0;
      if (blockIdx.x == 0) {
        flags[0] = sf[0];
        flags[1] = sf[1];
      }
    }
  }
  __syncthreads();
  const int f32 = sf[0], wide = sf[1];
  const int e0 = (blockIdx.x * 256 + tid) * 2;
  if (e0 >= E) return;
  const bool has1 = (e0 + 1 < E);
  int s0, s1, d0, d1;
  if (wide) {
    int4 vs = *(const int4*)(ei + 2 * (size_t)e0);
    int4 vd = *(const int4*)(ei + 2 * (size_t)E + 2 * (size_t)e0);
    s0 = vs.x; s1 = vs.z; d0 = vd.x; d1 = vd.z;
  } else {
    int2 vs = *(const int2*)(ei + e0);
    int2 vd = *(const int2*)(ei + (size_t)E + e0);
    s0 = vs.x; s1 = vs.y; d0 = vd.x; d1 = vd.y;
  }
  float w0, w1 = 0.f;
  if (f32) {
    float2 wv = *(const float2*)((const float*)w + e0);
    w0 = wv.x; w1 = wv.y;
  } else {
    const __hip_bfloat16* wb = (const __hip_bfloat16*)w;
    w0 = __bfloat162float(wb[e0]);
    if (has1) w1 = __bfloat162float(wb[e0 + 1]);
  }
  int d0c = min(max(d0, 0), N - 1);
  int slot0 = atomicAdd(&cnt[d0c], 1);
  if (slot0 < CAP)
    csr2[(size_t)d0c * CAP + slot0] = pack_sg(min(max(s0, 0), N - 1), gate_of(w0));
  if (has1) {
    int d1c = min(max(d1, 0), N - 1);
    int slot1 = atomicAdd(&cnt[d1c], 1);
    if (slot1 < CAP)
      csr2[(size_t)d1c * CAP + slot1] = pack_sg(min(max(s1, 0), N - 1), gate_of(w1));
  }
}

// standalone prep (legacy non-fused tier) — 64-thread, grid=N
__global__ void __launch_bounds__(64) k_prep(const void* __restrict__ xin,
                                             const void* __restrict__ W,
                                             const void* __restrict__ att,
                                             const int* __restrict__ flags,
                                             unsigned char* __restrict__ fhat,
                                             __hip_bfloat16* __restrict__ Hmat,
                                             float* __restrict__ a_l,
                                             float* __restrict__ a_r, int N) {
  __shared__ float ls[D];
  const int lane = threadIdx.x;
  const int wid = blockIdx.x;
  if (wid >= N) return;
  const int f32 = flags[0];
  float f = ldv(xin, (size_t)wid * D + lane, f32);
  prep_node(f, f32, wid, lane, W, att, fhat, Hmat, a_l, a_r, ls);
}

// ---------------- edge kernel: ONE wave per dst node (64-thread blocks) ----------------
// modes: 0=fused layer-1 prep epilogue (tier A/B), 1=in-kernel MLP (legacy),
//        2=store native, 3=v + xres -> out (tier A final)
__global__ void __launch_bounds__(64, 8) k_edge(const int* __restrict__ cnt,
                                                const unsigned int* __restrict__ csr2,
                                                const int* __restrict__ ei,
                                                const void* __restrict__ w,
                                                const unsigned char* __restrict__ fhat,
                                                const __hip_bfloat16* __restrict__ Hmat,
                                                const float* __restrict__ a_l,
                                                const float* __restrict__ a_r,
                                                const void* __restrict__ beta,
                                                const void* __restrict__ bias,
                                                const void* __restrict__ x,
                                                const void* __restrict__ rW1,
                                                const void* __restrict__ rb1,
                                                const void* __restrict__ rW2,
                                                const void* __restrict__ rb2,
                                                const void* __restrict__ Wn,
                                                const void* __restrict__ attn,
                                                unsigned char* __restrict__ fh2,
                                                __hip_bfloat16* __restrict__ Hm2,
                                                float* __restrict__ al2,
                                                float* __restrict__ ar2,
                                                const float* __restrict__ xres,
                                                const int* __restrict__ flags,
                                                void* __restrict__ out,
                                                int N, int E, int mode) {
  const int lane = threadIdx.x;
  const int wid = blockIdx.x;
  __shared__ float2 lc[CAP];  // (l, c) per edge
  __shared__ float2 sg[CAP];  // (src bits, p) — written in phase 2
  __shared__ float lds_t[D];  // acc transpose; reused as GEMM staging in epilogue
  if (wid >= N) return;
  const int f32 = flags[0];
  const int g = lane >> 3;   // edge slot in 8-edge group
  const int sub = lane & 7;  // feature block: [8*sub, 8*sub+8)
  const int degRaw = cnt[wid];
  const float aln = a_l[wid];
  const float bb = 1.f / (1.f + __expf(-ldv(beta, 0, f32)));
  const float ob = 1.f - bb;
  const char* HmatB = (const char*)Hmat;

  float v;  // pre-elu output feature for this lane
  if (degRaw <= CAP) {
    // ================= fast path (always taken on bench data) =================
    const int deg = degRaw;
    const int s = wid * CAP;
    float fn[8];
    dec_fp8x8(*(const uint2*)(fhat + (((unsigned)wid << 6) | ((unsigned)sub << 3))), fn);

    // ---- phase 1 (iters 0-3, static): fp8 gathers + Hmat prefetch to regs ----
    float m1 = -1e30f, m2 = -1e30f;
    uint4 hm[4];
#pragma unroll
    for (int kk = 0; kk < 4; ++kk) {
      const int base = kk * 8;
      if (base < deg) {
        const int j = base + g;
        const bool val = j < deg;
        const unsigned int en = val ? csr2[s + j] : (unsigned int)wid;
        const unsigned src = (unsigned)upk_src(en, N);
        float hv[8];
        dec_fp8x8(*(const uint2*)(fhat + ((src << 6) | ((unsigned)sub << 3))), hv);
        hm[kk] = *(const uint4*)(HmatB + ((src << 7) | ((unsigned)sub << 4)));
        float d = 0.f;
#pragma unroll
        for (int i = 0; i < 8; ++i) d += fn[i] * hv[i];
        d += __shfl_xor(d, 1, 64);
        d += __shfl_xor(d, 2, 64);
        d += __shfl_xor(d, 4, 64);
        float l = aln + a_r[src];
        l = (l >= 0.f) ? l : NEG_SLOPE * l;
        if (val) {
          m1 = fmaxf(m1, l);
          m2 = fmaxf(m2, d);
          if (sub == 0) lc[j] = make_float2(l, d);
        }
      }
    }
    // tail iterations (deg > 32): no prefetch
    for (int base = 32; base < deg; base += 8) {
      const int j = base + g;
      const bool val = j < deg;
      const unsigned int en = val ? csr2[s + j] : (unsigned int)wid;
      const unsigned src = (unsigned)upk_src(en, N);
      float hv[8];
      dec_fp8x8(*(const uint2*)(fhat + ((src << 6) | ((unsigned)sub << 3))), hv);
      float d = 0.f;
#pragma unroll
      for (int i = 0; i < 8; ++i) d += fn[i] * hv[i];
      d += __shfl_xor(d, 1, 64);
      d += __shfl_xor(d, 2, 64);
      d += __shfl_xor(d, 4, 64);
      float l = aln + a_r[src];
      l = (l >= 0.f) ? l : NEG_SLOPE * l;
      if (val) {
        m1 = fmaxf(m1, l);
        m2 = fmaxf(m2, d);
        if (sub == 0) lc[j] = make_float2(l, d);
      }
    }
    m1 = fmaxf(m1, __shfl_xor(m1, 8, 64));
    m1 = fmaxf(m1, __shfl_xor(m1, 16, 64));
    m1 = fmaxf(m1, __shfl_xor(m1, 32, 64));
    m2 = fmaxf(m2, __shfl_xor(m2, 8, 64));
    m2 = fmaxf(m2, __shfl_xor(m2, 16, 64));
    m2 = fmaxf(m2, __shfl_xor(m2, 32, 64));

    // ---- phase 2: dual softmax sums + fused p (deg <= 64 always) ----
    float el0 = 0.f, ec0 = 0.f, gg0 = 0.f;
    int q0 = 0;
    float ps1 = 0.f, ps2 = 0.f;
    if (lane < deg) {
      const unsigned int en = csr2[s + lane];  // coalesced, L2-hot
      q0 = upk_src(en, N);
      gg0 = upk_gate(en);
      float2 t = lc[lane];
      el0 = __expf(t.x - m1);
      ec0 = __expf(t.y - m2);
      ps1 = el0;
      ps2 = ec0;
    }
    const float rs1 = 1.f / (wred_sum(ps1) + EPS_SM);
    const float rs2 = 1.f / (wred_sum(ps2) + EPS_SM);

    float sp = 0.f;
    if (lane < deg) {
      float tt = (ob * el0 * rs1 + bb * ec0 * rs2) * gg0;
      float p0 = __expf(tt - 1.f);
      sp = p0;
      sg[lane] = make_float2(__int_as_float(q0), p0);  // (src, p)
    }
    const float rinv = 1.f / (wred_sum(sp) + EPS_SM);

    // ---- phase 3: register-resident Hmat for iters 0-3; gathers for tail ----
    float acc[8] = {0.f, 0.f, 0.f, 0.f, 0.f, 0.f, 0.f, 0.f};
#pragma unroll
    for (int kk = 0; kk < 4; ++kk) {
      const int base = kk * 8;
      if (base < deg) {
        const int j = base + g;
        const float pv = (j < deg) ? sg[j].y : 0.f;
        float hv[8];
        unp8(hm[kk], hv);
#pragma unroll
        for (int i = 0; i < 8; ++i) acc[i] += pv * hv[i];
      }
    }
    for (int base = 32; base < deg; base += 8) {
      const int j = base + g;
      float2 en = (j < deg) ? sg[j] : make_float2(__int_as_float(wid), 0.f);
      const float pv = en.y;
      const unsigned srcv = (unsigned)__float_as_int(en.x);
      float hv[8];
      unp8(*(const uint4*)(HmatB + ((srcv << 7) | ((unsigned)sub << 4))), hv);
#pragma unroll
      for (int i = 0; i < 8; ++i) acc[i] += pv * hv[i];
    }
#pragma unroll
    for (int i = 0; i < 8; ++i) {
      acc[i] += __shfl_xor(acc[i], 8, 64);
      acc[i] += __shfl_xor(acc[i], 16, 64);
      acc[i] += __shfl_xor(acc[i], 32, 64);
    }
    if (g == 0) {
#pragma unroll
      for (int i = 0; i < 8; ++i) lds_t[8 * sub + i] = acc[i];
    }
    v = lds_t[lane] * rinv + ldv(bias, lane, f32);
  } else {
    // ============ slow path: exact 3-pass over raw edge list ============
    const int wide = flags[1];
    lds_t[lane] = 0.f;
    float m1 = -1e30f, m2 = -1e30f;
    for (int e64 = lane; e64 < E; e64 += 64) {
      int dd = wide ? ei[2 * (size_t)E + 2 * (size_t)e64] : ei[(size_t)E + e64];
      if (dd != wid) continue;
      int ss = wide ? ei[2 * (size_t)e64] : ei[e64];
      ss = min(max(ss, 0), N - 1);
      float l = aln + a_r[ss];
      l = (l >= 0.f) ? l : NEG_SLOPE * l;
      float c = slow_cos(fhat, wid, ss);
      m1 = fmaxf(m1, l);
      m2 = fmaxf(m2, c);
    }
    m1 = wred_max(m1);
    m2 = wred_max(m2);
    float ps1 = 0.f, ps2 = 0.f;
    for (int e64 = lane; e64 < E; e64 += 64) {
      int dd = wide ? ei[2 * (size_t)E + 2 * (size_t)e64] : ei[(size_t)E + e64];
      if (dd != wid) continue;
      int ss = wide ? ei[2 * (size_t)e64] : ei[e64];
      ss = min(max(ss, 0), N - 1);
      float l = aln + a_r[ss];
      l = (l >= 0.f) ? l : NEG_SLOPE * l;
      float c = slow_cos(fhat, wid, ss);
      ps1 += __expf(l - m1);
      ps2 += __expf(c - m2);
    }
    const float rs1 = 1.f / (wred_sum(ps1) + EPS_SM);
    const float rs2 = 1.f / (wred_sum(ps2) + EPS_SM);
    float sp = 0.f;
    for (int e64 = lane; e64 < E; e64 += 64) {
      int dd = wide ? ei[2 * (size_t)E + 2 * (size_t)e64] : ei[(size_t)E + e64];
      if (dd != wid) continue;
      int ss = wide ? ei[2 * (size_t)e64] : ei[e64];
      ss = min(max(ss, 0), N - 1);
      float l = aln + a_r[ss];
      l = (l >= 0.f) ? l : NEG_SLOPE * l;
      float c = slow_cos(fhat, wid, ss);
      float gx = gate_of(ldv(w, e64, f32));
      float px = __expf((ob * __expf(l - m1) * rs1 + bb * __expf(c - m2) * rs2) * gx - 1.f);
      sp += px;
      for (int q = 0; q < D; ++q)
        atomicAdd(&lds_t[q], px * __bfloat162float(Hmat[(size_t)ss * D + q]));
    }
    const float rinv = 1.f / (wred_sum(sp) + EPS_SM);
    v = lds_t[lane] * rinv + ldv(bias, lane, f32);
  }

  v = elu1(v);  // elu inside _cosgat
  if (mode == 3) {
    float a2 = xres[(size_t)wid * D + lane];
    stv(out, (size_t)wid * D + lane, f32, sane(v + a2));
  } else if (mode == 1) {
    // legacy: fused residual MLP — LDS-broadcast GEMMs
    float xv = ldv(x, (size_t)wid * D + lane, f32);
    float b0_ = ldv(rb1, lane, f32);
    __syncthreads();
    lds_t[lane] = xv;
    __syncthreads();
    float a2;
    float h0 = 0.f, h1 = 0.f, h2 = 0.f, h3 = 0.f;
    if (f32) {
      const float* w1 = (const float*)rW1;
      const float* w2 = (const float*)rW2;
#pragma unroll 4
      for (int k = 0; k < D; k += 4) {
        h0 += lds_t[k] * w1[k * D + lane];
        h1 += lds_t[k + 1] * w1[(k + 1) * D + lane];
        h2 += lds_t[k + 2] * w1[(k + 2) * D + lane];
        h3 += lds_t[k + 3] * w1[(k + 3) * D + lane];
      }
      float tr = fmaxf(b0_ + (h0 + h1) + (h2 + h3), 0.f);
      __syncthreads();
      lds_t[lane] = tr;
      __syncthreads();
      float g0 = 0.f, g1 = 0.f, g2 = 0.f, g3 = 0.f;
#pragma unroll 4
      for (int k = 0; k < D; k += 4) {
        g0 += lds_t[k] * w2[k * D + lane];
        g1 += lds_t[k + 1] * w2[(k + 1) * D + lane];
        g2 += lds_t[k + 2] * w2[(k + 2) * D + lane];
        g3 += lds_t[k + 3] * w2[(k + 3) * D + lane];
      }
      a2 = ((const float*)rb2)[lane] + (g0 + g1) + (g2 + g3);
    } else {
      const __hip_bfloat16* w1 = (const __hip_bfloat16*)rW1;
      const __hip_bfloat16* w2 = (const __hip_bfloat16*)rW2;
#pragma unroll 4
      for (int k = 0; k < D; k += 4) {
        h0 += lds_t[k] * __bfloat162float(w1[k * D + lane]);
        h1 += lds_t[k + 1] * __bfloat162float(w1[(k + 1) * D + lane]);
        h2 += lds_t[k + 2] * __bfloat162float(w1[(k + 2) * D + lane]);
        h3 += lds_t[k + 3] * __bfloat162float(w1[(k + 3) * D + lane]);
      }
      float tr = fmaxf(b0_ + (h0 + h1) + (h2 + h3), 0.f);
      __syncthreads();
      lds_t[lane] = tr;
      __syncthreads();
      float g0 = 0.f, g1 = 0.f, g2 = 0.f, g3 = 0.f;
#pragma unroll 4
      for (int k = 0; k < D; k += 4) {
        g0 += lds_t[k] * __bfloat162float(w2[k * D + lane]);
        g1 += lds_t[k + 1] * __bfloat162float(w2[(k + 1) * D + lane]);
        g2 += lds_t[k + 2] * __bfloat162float(w2[(k + 2) * D + lane]);
        g3 += lds_t[k + 3] * __bfloat162float(w2[(k + 3) * D + lane]);
      }
      a2 = __bfloat162float(((const __hip_bfloat16*)rb2)[lane]) + (g0 + g1) + (g2 + g3);
    }
    stv(out, (size_t)wid * D + lane, f32, sane(v + a2));
  } else {
    v = elu1(v);  // inter-layer elu
    if (mode == 0) {
      __syncthreads();
      prep_node(sane(v), f32, wid, lane, Wn, attn, fh2, Hm2, al2, ar2, lds_t);
    } else {  // mode 2: store native dtype
      stv(out, (size_t)wid * D + lane, f32, sane(v));
    }
  }
}

extern "C" void kernel_launch(void* const* d_in, const int* in_sizes, int n_in,
                              void* d_out, int out_size, void* d_ws, size_t ws_size,
                              hipStream_t stream) {
  const void* x = d_in[0];
  const int* ei = (const int*)d_in[1];
  const void* w = d_in[2];
  const void* W0 = d_in[3];
  const void* att0 = d_in[4];
  const void* beta0 = d_in[5];
  const void* b0 = d_in[6];
  const void* W1 = d_in[7];
  const void* att1 = d_in[8];
  const void* beta1 = d_in[9];
  const void* b1 = d_in[10];
  const void* rW1 = d_in[11];
  const void* rb1 = d_in[12];
  const void* rW2 = d_in[13];
  const void* rb2 = d_in[14];

  const int N = in_sizes[0] / D;
  const int E = in_sizes[2];

  char* base = (char*)d_ws;
  size_t off = 0;
  auto alloc = [&](size_t bytes) -> void* {
    void* p = base + off;
    off += (bytes + 255) & ~(size_t)255;
    return p;
  };
  // common tier
  int* flags = (int*)alloc(256);
  int* cnt = (int*)alloc((size_t)N * 4);
  unsigned int* csr2 = (unsigned int*)alloc((size_t)N * CAP * 4);
  unsigned char* fhat = (unsigned char*)alloc((size_t)N * D);
  __hip_bfloat16* Hmat = (__hip_bfloat16*)alloc((size_t)N * D * 2);
  float* a_l = (float*)alloc((size_t)N * 4);
  float* a_r = (float*)alloc((size_t)N * 4);
  // layer-1 prep buffers (used by tier A and tier B)
  unsigned char* fhat2 = (unsigned char*)alloc((size_t)N * D);
  __hip_bfloat16* Hmat2 = (__hip_bfloat16*)alloc((size_t)N * D * 2);
  float* a_l2 = (float*)alloc((size_t)N * 4);
  float* a_r2 = (float*)alloc((size_t)N * 4);
  const bool tierB = (off <= ws_size);
  // tier A additionally needs xres
  float* xres = (float*)alloc((size_t)N * D * 4);
  const bool tierA = (off <= ws_size);

  const int eb2 = (E / 2 + 255) / 256;

  hipMemsetAsync(cnt, 0, (size_t)N * 4, stream);

  if (tierA) {
    // 4 dispatches: k_all (scatter+prep0+MLP) -> edge(mode0: fused prep1)
    //               -> edge(mode3: +xres -> out)
    k_all<<<N, 64, 0, stream>>>((const unsigned short*)x, ei, w, flags, cnt,
                                x, W0, att0, rW1, rb1, rW2, rb2,
                                fhat, Hmat, a_l, a_r, xres, csr2, N, E);
    k_edge<<<N, 64, 0, stream>>>(cnt, csr2, ei, w, fhat, Hmat, a_l, a_r,
                                 beta0, b0, x, rW1, rb1, rW2, rb2,
                                 W1, att1, fhat2, Hmat2, a_l2, a_r2,
                                 nullptr, flags, d_out, N, E, 0);
    k_edge<<<N, 64, 0, stream>>>(cnt, csr2, ei, w, fhat2, Hmat2, a_l2, a_r2,
                                 beta1, b1, x, rW1, rb1, rW2, rb2,
                                 nullptr, nullptr, nullptr, nullptr, nullptr, nullptr,
                                 xres, flags, d_out, N, E, 3);
  } else if (tierB) {
    k_bin<<<eb2, 256, 0, stream>>>((const unsigned short*)x, ei, w, flags, cnt,
                                   csr2, N, E);
    k_prep<<<N, 64, 0, stream>>>(x, W0, att0, flags, fhat, Hmat, a_l, a_r, N);
    k_edge<<<N, 64, 0, stream>>>(cnt, csr2, ei, w, fhat, Hmat, a_l, a_r,
                                 beta0, b0, x, rW1, rb1, rW2, rb2,
                                 W1, att1, fhat2, Hmat2, a_l2, a_r2,
                                 nullptr, flags, d_out, N, E, 0);
    k_edge<<<N, 64, 0, stream>>>(cnt, csr2, ei, w, fhat2, Hmat2, a_l2, a_r2,
                                 beta1, b1, x, rW1, rb1, rW2, rb2,
                                 nullptr, nullptr, nullptr, nullptr, nullptr, nullptr,
                                 nullptr, flags, d_out, N, E, 1);
  } else {
    k_bin<<<eb2, 256, 0, stream>>>((const unsigned short*)x, ei, w, flags, cnt,
                                   csr2, N, E);
    k_prep<<<N, 64, 0, stream>>>(x, W0, att0, flags, fhat, Hmat, a_l, a_r, N);
    k_edge<<<N, 64, 0, stream>>>(cnt, csr2, ei, w, fhat, Hmat, a_l, a_r,
                                 beta0, b0, x, rW1, rb1, rW2, rb2,
                                 nullptr, nullptr, nullptr, nullptr, nullptr, nullptr,
                                 nullptr, flags, d_out, N, E, 2);
    k_prep<<<N, 64, 0, stream>>>(d_out, W1, att1, flags, fhat, Hmat, a_l, a_r, N);
    k_edge<<<N, 64, 0, stream>>>(cnt, csr2, ei, w, fhat, Hmat, a_l, a_r,
                                 beta1, b1, x, rW1, rb1, rW2, rb2,
                                 nullptr, nullptr, nullptr, nullptr, nullptr, nullptr,
                                 nullptr, flags, d_out, N, E, 1);
  }
}